// Round 1
// 201.767 us; speedup vs baseline: 1.0012x; 1.0012x over previous
//
#include <hip/hip_runtime.h>
#include <hip/hip_bf16.h>

using bf16 = __hip_bfloat16;
typedef __attribute__((ext_vector_type(8))) short frag8;   // 8 bf16 (4 VGPRs)
typedef __attribute__((ext_vector_type(4))) float f32x4;   // 4 fp32 acc

constexpr int   H_   = 1024;               // N_EMBD
constexpr int   B_   = 8;                  // BATCH
constexpr int   T_   = 2048;
constexpr int   K_   = H_;
constexpr int   N_   = H_;
constexpr long  M_   = (long)B_ * T_;      // 16384
constexpr int   SEG  = 64;                 // segments per sequence (R3: 32 -> 64 for 2x scan parallelism)
constexpr int   TSEG = T_ / SEG;           // 32
constexpr int   NCH  = B_ * H_;            // 8192 channels
constexpr int   NVC  = NCH / 4;            // 2048 vec4-channels

__device__ __forceinline__ unsigned short f2bf(float f) {
  bf16 b = __float2bfloat16(f);
  return *reinterpret_cast<unsigned short*>(&b);
}

__device__ __forceinline__ float4 fma4(float4 h, float4 a, float4 v) {
  float4 r;
  r.x = fmaf(h.x, a.x, v.x);
  r.y = fmaf(h.y, a.y, v.y);
  r.z = fmaf(h.z, a.z, v.z);
  r.w = fmaf(h.w, a.w, v.w);
  return r;
}

// ---------------- fp32 -> bf16 convert (x then B) + fused sigmoid ----------------
__global__ __launch_bounds__(256) void k_convert(const float* __restrict__ x,
                                                 const float* __restrict__ Bm,
                                                 const float* __restrict__ raw,
                                                 unsigned short* __restrict__ xb,
                                                 unsigned short* __restrict__ Bb,
                                                 float* __restrict__ a_sig) {
  const long NX4 = (M_ * K_) / 4;             // 4194304
  const long NB4 = ((long)N_ * K_) / 4;       // 262144
  long t = (long)blockIdx.x * 256 + threadIdx.x;
  const float* src; unsigned short* dst;
  if (t < NX4) { src = x; dst = xb; }
  else if (t < NX4 + NB4) { t -= NX4; src = Bm; dst = Bb; }
  else {
    long q = t - NX4 - NB4;
    if (q >= H_ / 4) return;
    float4 v = *reinterpret_cast<const float4*>(raw + q * 4);
    float4 o;
    o.x = 1.0f / (1.0f + expf(-v.x));
    o.y = 1.0f / (1.0f + expf(-v.y));
    o.z = 1.0f / (1.0f + expf(-v.z));
    o.w = 1.0f / (1.0f + expf(-v.w));
    *reinterpret_cast<float4*>(a_sig + q * 4) = o;
    return;
  }
  long i = t * 4;
  float4 v = *reinterpret_cast<const float4*>(src + i);
  short4 o;
  o.x = (short)f2bf(v.x);
  o.y = (short)f2bf(v.y);
  o.z = (short)f2bf(v.z);
  o.w = (short)f2bf(v.w);
  *reinterpret_cast<short4*>(dst + i) = o;
}

// ---------------- bf16 GEMM (m97 structure): C[m][n] = sum_k A[m,k]*B[n,k] ----------------
__global__ __launch_bounds__(256) void k_gemm(const unsigned short* __restrict__ A,
                                              const unsigned short* __restrict__ Bb,
                                              float* __restrict__ C) {
  constexpr int BK = 32;
  __shared__ __align__(16) unsigned short lA[128 * BK];   // 8 KiB
  __shared__ __align__(16) unsigned short lB[128 * BK];   // 8 KiB
  const int tid  = threadIdx.x;
  const int lane = tid & 63;
  const int wave = tid >> 6;
  const long m0 = (long)blockIdx.x * 128;
  const long n0 = (long)blockIdx.y * 128;
  const int wm = (wave >> 1) * 64;
  const int wn = (wave & 1) * 64;
  const int quad = lane >> 4;
  const int l16  = lane & 15;

  const unsigned short* gA = A  + (m0 + (tid >> 2)) * K_ + (tid & 3) * 8;
  const unsigned short* gB = Bb + (n0 + (tid >> 2)) * K_ + (tid & 3) * 8;
  unsigned short* sA = &lA[(tid & ~63) * 8];
  unsigned short* sB = &lB[(tid & ~63) * 8];

  f32x4 acc[4][4];
  #pragma unroll
  for (int i = 0; i < 4; i++)
    #pragma unroll
    for (int j = 0; j < 4; j++)
      acc[i][j] = f32x4{0.f, 0.f, 0.f, 0.f};

  for (int k0 = 0; k0 < K_; k0 += BK) {
    __builtin_amdgcn_global_load_lds(
        (const __attribute__((address_space(1))) void*)(gA + k0),
        (__attribute__((address_space(3))) void*)sA, 16, 0, 0);
    __builtin_amdgcn_global_load_lds(
        (const __attribute__((address_space(1))) void*)(gA + 64 * K_ + k0),
        (__attribute__((address_space(3))) void*)(sA + 64 * BK), 16, 0, 0);
    __builtin_amdgcn_global_load_lds(
        (const __attribute__((address_space(1))) void*)(gB + k0),
        (__attribute__((address_space(3))) void*)sB, 16, 0, 0);
    __builtin_amdgcn_global_load_lds(
        (const __attribute__((address_space(1))) void*)(gB + 64 * K_ + k0),
        (__attribute__((address_space(3))) void*)(sB + 64 * BK), 16, 0, 0);
    __syncthreads();

    frag8 af[4], bfr[4];
    #pragma unroll
    for (int i = 0; i < 4; i++) {
      af[i]  = *reinterpret_cast<const frag8*>(&lA[(wm + i * 16 + l16) * BK + quad * 8]);
      bfr[i] = *reinterpret_cast<const frag8*>(&lB[(wn + i * 16 + l16) * BK + quad * 8]);
    }
    #pragma unroll
    for (int i = 0; i < 4; i++)
      #pragma unroll
      for (int j = 0; j < 4; j++)
        acc[i][j] = __builtin_amdgcn_mfma_f32_16x16x32_bf16(af[i], bfr[j], acc[i][j], 0, 0, 0);
    __syncthreads();
  }

  #pragma unroll
  for (int i = 0; i < 4; i++)
    #pragma unroll
    for (int j = 0; j < 4; j++) {
      long r0 = m0 + wm + i * 16 + quad * 4;
      long c0 = n0 + wn + j * 16 + l16;
      #pragma unroll
      for (int r = 0; r < 4; r++)
        C[(r0 + r) * N_ + c0] = acc[i][j][r];
    }
}

// ---------------- scan phase 1: per-segment local end-states ----------------
// R3: 8-deep batched loads for MLP (was 1 outstanding 16B load/thread -> latency-bound)
__global__ __launch_bounds__(256) void k_seg_ends(const float* __restrict__ u,
                                                  const float* __restrict__ a_sig,
                                                  float* __restrict__ E) {
  int g = blockIdx.x * 256 + threadIdx.x;   // 0 .. NVC*SEG-1 = 131071
  int vc = g & (NVC - 1);                   // 0..2047 (vec4 channel)
  int s  = g >> 11;                         // segment 0..63
  int b  = vc >> 8;                         // batch
  int h4 = (vc & 255) * 4;                  // first of 4 h-channels
  float4 a = *reinterpret_cast<const float4*>(a_sig + h4);
  const float* base = u + (long)b * T_ * H_ + (long)s * TSEG * H_ + h4;
  float4 e = {0.f, 0.f, 0.f, 0.f};
  #pragma unroll
  for (int t0 = 0; t0 < TSEG; t0 += 8) {
    float4 v[8];
    #pragma unroll
    for (int j = 0; j < 8; j++)
      v[j] = *reinterpret_cast<const float4*>(base + (long)(t0 + j) * H_);
    #pragma unroll
    for (int j = 0; j < 8; j++)
      e = fma4(e, a, v[j]);
  }
  *reinterpret_cast<float4*>(E + (long)g * 4) = e;
}

// ---------------- scan phase 2: carry chain across segments (in-place on EC) ----------------
// EC[s*NCH+c] on entry: segment-end local states; on exit: carry INTO segment s.
__global__ __launch_bounds__(256) void k_carries(float* __restrict__ EC,
                                                 const float* __restrict__ h0,
                                                 const float* __restrict__ a_sig) {
  int c = blockIdx.x * 256 + threadIdx.x;   // 0..8191
  if (c >= NCH) return;
  float a = a_sig[c & (H_ - 1)];
  float aL = a;
  #pragma unroll
  for (int i = 0; i < 5; i++) aL *= aL;     // a^32 = a^TSEG
  float carry = h0[c];
  #pragma unroll
  for (int s0 = 0; s0 < SEG; s0 += 8) {
    float e[8];
    #pragma unroll
    for (int j = 0; j < 8; j++) e[j] = EC[(long)(s0 + j) * NCH + c];
    #pragma unroll
    for (int j = 0; j < 8; j++) {
      EC[(long)(s0 + j) * NCH + c] = carry;
      carry = fmaf(aL, carry, e[j]);
    }
  }
}

// ---------------- scan phase 3: final scan with carry-in, in-place ----------------
// R3: register double-buffered batches of 8 (load next batch before storing current)
__global__ __launch_bounds__(256) void k_scan(float* __restrict__ u,
                                              const float* __restrict__ Cc,
                                              const float* __restrict__ a_sig) {
  int g = blockIdx.x * 256 + threadIdx.x;
  int vc = g & (NVC - 1);
  int s  = g >> 11;
  int b  = vc >> 8;
  int h4 = (vc & 255) * 4;
  float4 a = *reinterpret_cast<const float4*>(a_sig + h4);
  float4 hs = *reinterpret_cast<const float4*>(Cc + (long)g * 4);
  float* base = u + (long)b * T_ * H_ + (long)s * TSEG * H_ + h4;

  float4 v0[8], v1[8];
  #pragma unroll
  for (int j = 0; j < 8; j++)
    v0[j] = *reinterpret_cast<const float4*>(base + (long)j * H_);

  #pragma unroll
  for (int t0 = 0; t0 < TSEG; t0 += 8) {
    const bool odd = (t0 >> 3) & 1;          // compile-time after full unroll
    float4* cur = odd ? v1 : v0;
    float4* nxt = odd ? v0 : v1;
    if (t0 + 8 < TSEG) {
      #pragma unroll
      for (int j = 0; j < 8; j++)
        nxt[j] = *reinterpret_cast<const float4*>(base + (long)(t0 + 8 + j) * H_);
    }
    #pragma unroll
    for (int j = 0; j < 8; j++) {
      hs = fma4(hs, a, cur[j]);
      cur[j] = hs;
    }
    #pragma unroll
    for (int j = 0; j < 8; j++)
      *reinterpret_cast<float4*>(base + (long)(t0 + j) * H_) = cur[j];
  }
}

extern "C" void kernel_launch(void* const* d_in, const int* in_sizes, int n_in,
                              void* d_out, int out_size, void* d_ws, size_t ws_size,
                              hipStream_t stream) {
  const float* x    = (const float*)d_in[0];   // [8,2048,1024]
  const float* rawa = (const float*)d_in[1];   // [1024]
  const float* Bm   = (const float*)d_in[2];   // [1024,1024]
  const float* h0   = (const float*)d_in[3];   // [8,1024]
  float* u = (float*)d_out;                    // u then y, in place

  // Workspace layout — same 36 MiB + 4 KiB footprint as the verified R2 run:
  // xb 32 MiB | Bb 2 MiB | a_sig 4 KiB | EC 2 MiB (E and Cc share, in-place)
  char* w = (char*)d_ws;
  unsigned short* xb = (unsigned short*)w;                               // 32 MiB
  unsigned short* Bb = (unsigned short*)(w + 33554432);                  // 2 MiB
  float* a_sig = (float*)(w + 33554432 + 2097152);                       // 4 KiB
  float* EC    = (float*)(w + 33554432 + 2097152 + 4096);                // 2 MiB

  hipLaunchKernelGGL(k_convert, dim3(17409), dim3(256), 0, stream, x, Bm, rawa, xb, Bb, a_sig);
  hipLaunchKernelGGL(k_gemm, dim3(128, 8), dim3(256), 0, stream, xb, Bb, u);
  hipLaunchKernelGGL(k_seg_ends, dim3(NVC * SEG / 256), dim3(256), 0, stream, u, a_sig, EC);
  hipLaunchKernelGGL(k_carries, dim3(NCH / 256), dim3(256), 0, stream, EC, h0, a_sig);
  hipLaunchKernelGGL(k_scan, dim3(NVC * SEG / 256), dim3(256), 0, stream, u, EC, a_sig);
}

// Round 3
// 196.908 us; speedup vs baseline: 1.0259x; 1.0247x over previous
//
#include <hip/hip_runtime.h>
#include <hip/hip_bf16.h>

using bf16 = __hip_bfloat16;
typedef __attribute__((ext_vector_type(8))) short frag8;   // 8 bf16 (4 VGPRs)
typedef __attribute__((ext_vector_type(4))) float f32x4;   // 4 fp32 acc

constexpr int   H_   = 1024;               // N_EMBD
constexpr int   B_   = 8;                  // BATCH
constexpr int   T_   = 2048;
constexpr int   K_   = H_;
constexpr int   N_   = H_;
constexpr long  M_   = (long)B_ * T_;      // 16384
constexpr int   SEG  = 64;                 // segments per sequence
constexpr int   TSEG = T_ / SEG;           // 32
constexpr int   NCH  = B_ * H_;            // 8192 channels
constexpr int   NVC  = NCH / 4;            // 2048 vec4-channels

__device__ __forceinline__ unsigned short f2bf(float f) {
  bf16 b = __float2bfloat16(f);
  return *reinterpret_cast<unsigned short*>(&b);
}

__device__ __forceinline__ float4 fma4(float4 h, float4 a, float4 v) {
  float4 r;
  r.x = fmaf(h.x, a.x, v.x);
  r.y = fmaf(h.y, a.y, v.y);
  r.z = fmaf(h.z, a.z, v.z);
  r.w = fmaf(h.w, a.w, v.w);
  return r;
}

// ---------------- fp32 -> bf16 convert (x then B) + fused sigmoid (R1-verified) ----------------
__global__ __launch_bounds__(256) void k_convert(const float* __restrict__ x,
                                                 const float* __restrict__ Bm,
                                                 const float* __restrict__ raw,
                                                 unsigned short* __restrict__ xb,
                                                 unsigned short* __restrict__ Bb,
                                                 float* __restrict__ a_sig) {
  const long NX4 = (M_ * K_) / 4;             // 4194304
  const long NB4 = ((long)N_ * K_) / 4;       // 262144
  long t = (long)blockIdx.x * 256 + threadIdx.x;
  const float* src; unsigned short* dst;
  if (t < NX4) { src = x; dst = xb; }
  else if (t < NX4 + NB4) { t -= NX4; src = Bm; dst = Bb; }
  else {
    long q = t - NX4 - NB4;
    if (q >= H_ / 4) return;
    float4 v = *reinterpret_cast<const float4*>(raw + q * 4);
    float4 o;
    o.x = 1.0f / (1.0f + expf(-v.x));
    o.y = 1.0f / (1.0f + expf(-v.y));
    o.z = 1.0f / (1.0f + expf(-v.z));
    o.w = 1.0f / (1.0f + expf(-v.w));
    *reinterpret_cast<float4*>(a_sig + q * 4) = o;
    return;
  }
  long i = t * 4;
  float4 v = *reinterpret_cast<const float4*>(src + i);
  short4 o;
  o.x = (short)f2bf(v.x);
  o.y = (short)f2bf(v.y);
  o.z = (short)f2bf(v.z);
  o.w = (short)f2bf(v.w);
  *reinterpret_cast<short4*>(dst + i) = o;
}

// ---------------- bf16 GEMM: 256x256 tile, BK=64, 8-wave, 8-phase counted-vmcnt pipeline ----------------
// C[m][n] = sum_k A[m,k]*B[n,k].  Grid = 256 blocks (64 m-tiles x 4 n-tiles), 512 threads.
// LDS 128 KiB: lA/lB each [2 dbuf][2 half][128 rows][64 cols] bf16.
// Tile t lives in dbuf[t&1]; its 4 halves (A0,A1,B0,B1) are staged at global
// phases 4t-4..4t-1 and consumed at 4t+1..4t+4. Per-wave outstanding at each
// phase-4/8 boundary = 1 half (2 loads) -> s_waitcnt vmcnt(2). Buffer-free
// invariant: dbuf reads complete by barrier ending phase 4t+3; first
// overwrite issues at phase 4t+4.
#define MEMBAR asm volatile("" ::: "memory")
#define BARR do { MEMBAR; __builtin_amdgcn_s_barrier(); MEMBAR; } while (0)
#define VMW(n) asm volatile("s_waitcnt vmcnt(" #n ")" ::: "memory")
#define GLDS(SRC, DST) __builtin_amdgcn_global_load_lds( \
    (const __attribute__((address_space(1))) void*)(SRC), \
    (__attribute__((address_space(3))) void*)(DST), 16, 0, 0)

__global__ __launch_bounds__(512, 2) void k_gemm(const unsigned short* __restrict__ A,
                                                 const unsigned short* __restrict__ Bb,
                                                 float* __restrict__ C) {
  __shared__ __align__(16) unsigned short lA[32768];   // 64 KiB
  __shared__ __align__(16) unsigned short lB[32768];   // 64 KiB
  const int tid  = threadIdx.x;
  const int wid  = tid >> 6, lane = tid & 63;
  const int wr   = wid >> 2, wc = wid & 3;             // 2x4 wave grid
  const int quad = lane >> 4, l16 = lane & 15;
  const int bh   = wc >> 1, br = (wc & 1) * 64;        // B half / row base for this wave
  const int bid  = blockIdx.x;
  const int wgid = (bid & 7) * 32 + (bid >> 3);        // XCD-chunked swizzle (256%8==0, bijective)
  const long m0 = (long)(wgid >> 2) * 256;
  const long n0 = (long)(wgid & 3) * 256;
  const unsigned short* gA = A  + (m0 + (tid >> 3)) * K_ + (tid & 7) * 8;
  const unsigned short* gB = Bb + (n0 + (tid >> 3)) * K_ + (tid & 7) * 8;
  unsigned short* sAw = lA + wid * 512;                // wave-uniform LDS dest slice
  unsigned short* sBw = lB + wid * 512;

#define STG_A(d, hf, t) do { \
    GLDS(gA + ((hf) * 128) * K_ + (t) * 64,      sAw + (d) * 16384 + (hf) * 8192); \
    GLDS(gA + ((hf) * 128 + 64) * K_ + (t) * 64, sAw + (d) * 16384 + (hf) * 8192 + 4096); } while (0)
#define STG_B(d, hf, t) do { \
    GLDS(gB + ((hf) * 128) * K_ + (t) * 64,      sBw + (d) * 16384 + (hf) * 8192); \
    GLDS(gB + ((hf) * 128 + 64) * K_ + (t) * 64, sBw + (d) * 16384 + (hf) * 8192 + 4096); } while (0)

  f32x4 acc[8][4];
  #pragma unroll
  for (int i = 0; i < 8; i++)
    #pragma unroll
    for (int j = 0; j < 4; j++) acc[i][j] = f32x4{0.f, 0.f, 0.f, 0.f};

  frag8 aR[4][2];        // current ih-half A frags: [ii][ks]
  frag8 bR[2][2][2];     // both jh halves live:    [jh][jj][ks]

#define RD_A(d, ih) do { _Pragma("unroll") \
    for (int ii = 0; ii < 4; ii++) { \
      const unsigned short* p = lA + (d) * 16384 + wr * 8192 + (((ih) * 4 + ii) * 16 + l16) * 64 + quad * 8; \
      aR[ii][0] = *(const frag8*)p; \
      aR[ii][1] = *(const frag8*)(p + 32); } } while (0)
#define RD_B(d, jh) do { _Pragma("unroll") \
    for (int jj = 0; jj < 2; jj++) { \
      const unsigned short* p = lB + (d) * 16384 + bh * 8192 + (br + ((jh) * 2 + jj) * 16 + l16) * 64 + quad * 8; \
      bR[jh][jj][0] = *(const frag8*)p; \
      bR[jh][jj][1] = *(const frag8*)(p + 32); } } while (0)
#define MMQ(ih, jh) do { __builtin_amdgcn_s_setprio(1); _Pragma("unroll") \
    for (int ii = 0; ii < 4; ii++) { _Pragma("unroll") \
      for (int jj = 0; jj < 2; jj++) { \
        acc[(ih)*4+ii][(jh)*2+jj] = __builtin_amdgcn_mfma_f32_16x16x32_bf16(aR[ii][0], bR[jh][jj][0], acc[(ih)*4+ii][(jh)*2+jj], 0, 0, 0); \
        acc[(ih)*4+ii][(jh)*2+jj] = __builtin_amdgcn_mfma_f32_16x16x32_bf16(aR[ii][1], bR[jh][jj][1], acc[(ih)*4+ii][(jh)*2+jj], 0, 0, 0); } } \
    __builtin_amdgcn_s_setprio(0); } while (0)

  // prologue: tile0 all 4 halves + tile1 half A0 (5 halves = 10 loads); need tile0 -> vmcnt(2)
  STG_A(0, 0, 0); STG_A(0, 1, 0); STG_B(0, 0, 0); STG_B(0, 1, 0); STG_A(1, 0, 1);
  VMW(2); BARR;

  for (int it = 0; it < 7; ++it) {
    const int to = 2 * it + 1, te2 = 2 * it + 2, to2 = 2 * it + 3;
    RD_A(0, 0); RD_B(0, 0); STG_A(1, 1, to);  BARR; MMQ(0, 0);         BARR;  // p1
    RD_B(0, 1);             STG_B(1, 0, to);  BARR; MMQ(0, 1);         BARR;  // p2
    RD_A(0, 1);             STG_B(1, 1, to);  BARR; MMQ(1, 1);         BARR;  // p3
                            STG_A(0, 0, te2); BARR; MMQ(1, 0); VMW(2); BARR;  // p4
    RD_A(1, 0); RD_B(1, 0); STG_A(0, 1, te2); BARR; MMQ(0, 0);         BARR;  // p5
    RD_B(1, 1);             STG_B(0, 0, te2); BARR; MMQ(0, 1);         BARR;  // p6
    RD_A(1, 1);             STG_B(0, 1, te2); BARR; MMQ(1, 1);         BARR;  // p7
                            STG_A(1, 0, to2); BARR; MMQ(1, 0); VMW(2); BARR;  // p8
  }
  // peeled final iteration (tiles 14, 15): p1-3 still stage tile15's remaining halves
  RD_A(0, 0); RD_B(0, 0); STG_A(1, 1, 15); BARR; MMQ(0, 0);         BARR;
  RD_B(0, 1);             STG_B(1, 0, 15); BARR; MMQ(0, 1);         BARR;
  RD_A(0, 1);             STG_B(1, 1, 15); BARR; MMQ(1, 1);         BARR;
                                           BARR; MMQ(1, 0); VMW(0); BARR;
  RD_A(1, 0); RD_B(1, 0);                  BARR; MMQ(0, 0);         BARR;
  RD_B(1, 1);                              BARR; MMQ(0, 1);         BARR;
  RD_A(1, 1);                              BARR; MMQ(1, 1);         BARR;
  MMQ(1, 0);

  // epilogue: C/D layout col=l16, row=quad*4+r (m89-verified mapping)
  #pragma unroll
  for (int i = 0; i < 8; i++)
    #pragma unroll
    for (int j = 0; j < 4; j++) {
      const long r0 = m0 + wr * 128 + i * 16 + quad * 4;
      const long c0 = n0 + wc * 64 + j * 16 + l16;
      #pragma unroll
      for (int r = 0; r < 4; r++)
        C[(r0 + r) * N_ + c0] = acc[i][j][r];
    }
}

// ---------------- scan phase 1: per-segment local end-states (R1-verified) ----------------
__global__ __launch_bounds__(256) void k_seg_ends(const float* __restrict__ u,
                                                  const float* __restrict__ a_sig,
                                                  float* __restrict__ E) {
  int g = blockIdx.x * 256 + threadIdx.x;   // 0 .. NVC*SEG-1 = 131071
  int vc = g & (NVC - 1);                   // 0..2047 (vec4 channel)
  int s  = g >> 11;                         // segment 0..63
  int b  = vc >> 8;                         // batch
  int h4 = (vc & 255) * 4;                  // first of 4 h-channels
  float4 a = *reinterpret_cast<const float4*>(a_sig + h4);
  const float* base = u + (long)b * T_ * H_ + (long)s * TSEG * H_ + h4;
  float4 e = {0.f, 0.f, 0.f, 0.f};
  #pragma unroll
  for (int t0 = 0; t0 < TSEG; t0 += 8) {
    float4 v[8];
    #pragma unroll
    for (int j = 0; j < 8; j++)
      v[j] = *reinterpret_cast<const float4*>(base + (long)(t0 + j) * H_);
    #pragma unroll
    for (int j = 0; j < 8; j++)
      e = fma4(e, a, v[j]);
  }
  *reinterpret_cast<float4*>(E + (long)g * 4) = e;
}

// ---------------- scan phase 2: carry chain across segments (R1-verified, in-place on EC) ----------------
__global__ __launch_bounds__(256) void k_carries(float* __restrict__ EC,
                                                 const float* __restrict__ h0,
                                                 const float* __restrict__ a_sig) {
  int c = blockIdx.x * 256 + threadIdx.x;   // 0..8191
  if (c >= NCH) return;
  float a = a_sig[c & (H_ - 1)];
  float aL = a;
  #pragma unroll
  for (int i = 0; i < 5; i++) aL *= aL;     // a^32 = a^TSEG
  float carry = h0[c];
  #pragma unroll
  for (int s0 = 0; s0 < SEG; s0 += 8) {
    float e[8];
    #pragma unroll
    for (int j = 0; j < 8; j++) e[j] = EC[(long)(s0 + j) * NCH + c];
    #pragma unroll
    for (int j = 0; j < 8; j++) {
      EC[(long)(s0 + j) * NCH + c] = carry;
      carry = fmaf(aL, carry, e[j]);
    }
  }
}

// ---------------- scan phase 3: final scan with carry-in, in-place (R1-verified) ----------------
__global__ __launch_bounds__(256) void k_scan(float* __restrict__ u,
                                              const float* __restrict__ Cc,
                                              const float* __restrict__ a_sig) {
  int g = blockIdx.x * 256 + threadIdx.x;
  int vc = g & (NVC - 1);
  int s  = g >> 11;
  int b  = vc >> 8;
  int h4 = (vc & 255) * 4;
  float4 a = *reinterpret_cast<const float4*>(a_sig + h4);
  float4 hs = *reinterpret_cast<const float4*>(Cc + (long)g * 4);
  float* base = u + (long)b * T_ * H_ + (long)s * TSEG * H_ + h4;

  float4 v0[8], v1[8];
  #pragma unroll
  for (int j = 0; j < 8; j++)
    v0[j] = *reinterpret_cast<const float4*>(base + (long)j * H_);

  #pragma unroll
  for (int t0 = 0; t0 < TSEG; t0 += 8) {
    const bool odd = (t0 >> 3) & 1;          // compile-time after full unroll
    float4* cur = odd ? v1 : v0;
    float4* nxt = odd ? v0 : v1;
    if (t0 + 8 < TSEG) {
      #pragma unroll
      for (int j = 0; j < 8; j++)
        nxt[j] = *reinterpret_cast<const float4*>(base + (long)(t0 + 8 + j) * H_);
    }
    #pragma unroll
    for (int j = 0; j < 8; j++) {
      hs = fma4(hs, a, cur[j]);
      cur[j] = hs;
    }
    #pragma unroll
    for (int j = 0; j < 8; j++)
      *reinterpret_cast<float4*>(base + (long)(t0 + j) * H_) = cur[j];
  }
}

extern "C" void kernel_launch(void* const* d_in, const int* in_sizes, int n_in,
                              void* d_out, int out_size, void* d_ws, size_t ws_size,
                              hipStream_t stream) {
  const float* x    = (const float*)d_in[0];   // [8,2048,1024]
  const float* rawa = (const float*)d_in[1];   // [1024]
  const float* Bm   = (const float*)d_in[2];   // [1024,1024]
  const float* h0   = (const float*)d_in[3];   // [8,1024]
  float* u = (float*)d_out;                    // u then y, in place

  // Workspace layout (R1-verified footprint):
  // xb 32 MiB | Bb 2 MiB | a_sig 4 KiB | EC 2 MiB
  char* w = (char*)d_ws;
  unsigned short* xb = (unsigned short*)w;                               // 32 MiB
  unsigned short* Bb = (unsigned short*)(w + 33554432);                  // 2 MiB
  float* a_sig = (float*)(w + 33554432 + 2097152);                       // 4 KiB
  float* EC    = (float*)(w + 33554432 + 2097152 + 4096);                // 2 MiB

  hipLaunchKernelGGL(k_convert, dim3(17409), dim3(256), 0, stream, x, Bm, rawa, xb, Bb, a_sig);
  hipLaunchKernelGGL(k_gemm, dim3(256), dim3(512), 0, stream, xb, Bb, u);
  hipLaunchKernelGGL(k_seg_ends, dim3(NVC * SEG / 256), dim3(256), 0, stream, u, a_sig, EC);
  hipLaunchKernelGGL(k_carries, dim3(NCH / 256), dim3(256), 0, stream, EC, h0, a_sig);
  hipLaunchKernelGGL(k_scan, dim3(NVC * SEG / 256), dim3(256), 0, stream, u, EC, a_sig);
}

// Round 4
// 185.356 us; speedup vs baseline: 1.0898x; 1.0623x over previous
//
#include <hip/hip_runtime.h>
#include <hip/hip_bf16.h>

using bf16 = __hip_bfloat16;
typedef __attribute__((ext_vector_type(8))) short frag8;   // 8 bf16 (4 VGPRs)
typedef __attribute__((ext_vector_type(4))) float f32x4;   // 4 fp32 acc

constexpr int   H_   = 1024;               // N_EMBD
constexpr int   B_   = 8;                  // BATCH
constexpr int   T_   = 2048;
constexpr int   K_   = H_;
constexpr int   N_   = H_;
constexpr long  M_   = (long)B_ * T_;      // 16384
constexpr int   SEG  = 64;                 // segments per sequence
constexpr int   TSEG = T_ / SEG;           // 32
constexpr int   NCH  = B_ * H_;            // 8192 channels
constexpr int   NVC  = NCH / 4;            // 2048 vec4-channels

__device__ __forceinline__ unsigned short f2bf(float f) {
  bf16 b = __float2bfloat16(f);
  return *reinterpret_cast<unsigned short*>(&b);
}

__device__ __forceinline__ float4 fma4(float4 h, float4 a, float4 v) {
  float4 r;
  r.x = fmaf(h.x, a.x, v.x);
  r.y = fmaf(h.y, a.y, v.y);
  r.z = fmaf(h.z, a.z, v.z);
  r.w = fmaf(h.w, a.w, v.w);
  return r;
}

// ---------------- fp32 -> bf16 convert (x then B) + fused sigmoid (R1-verified) ----------------
__global__ __launch_bounds__(256) void k_convert(const float* __restrict__ x,
                                                 const float* __restrict__ Bm,
                                                 const float* __restrict__ raw,
                                                 unsigned short* __restrict__ xb,
                                                 unsigned short* __restrict__ Bb,
                                                 float* __restrict__ a_sig) {
  const long NX4 = (M_ * K_) / 4;             // 4194304
  const long NB4 = ((long)N_ * K_) / 4;       // 262144
  long t = (long)blockIdx.x * 256 + threadIdx.x;
  const float* src; unsigned short* dst;
  if (t < NX4) { src = x; dst = xb; }
  else if (t < NX4 + NB4) { t -= NX4; src = Bm; dst = Bb; }
  else {
    long q = t - NX4 - NB4;
    if (q >= H_ / 4) return;
    float4 v = *reinterpret_cast<const float4*>(raw + q * 4);
    float4 o;
    o.x = 1.0f / (1.0f + expf(-v.x));
    o.y = 1.0f / (1.0f + expf(-v.y));
    o.z = 1.0f / (1.0f + expf(-v.z));
    o.w = 1.0f / (1.0f + expf(-v.w));
    *reinterpret_cast<float4*>(a_sig + q * 4) = o;
    return;
  }
  long i = t * 4;
  float4 v = *reinterpret_cast<const float4*>(src + i);
  short4 o;
  o.x = (short)f2bf(v.x);
  o.y = (short)f2bf(v.y);
  o.z = (short)f2bf(v.z);
  o.w = (short)f2bf(v.w);
  *reinterpret_cast<short4*>(dst + i) = o;
}

// ---------------- bf16 GEMM: 256x256 tile, BK=64, 8-wave, 8-phase counted-vmcnt pipeline ----------------
// R4: + T2 XOR swizzle (rule 21: linear LDS dest, inverse-swizzled GLOBAL source,
// same-involution swizzled reads). Tile rows are 128B (64 bf16); slot = 16B granule
// index 0..7; swizzle: slot ^= (row & 7). Stager: thread tid has linear LDS dest
// (row=tid>>3, slot=tid&7), so its global source col-granule is (tid&7)^((tid>>3)&7)
// — all staged row offsets (64,128) and K offsets (t*64) preserve row&7 and the
// granule window. Readers: every RD row base is a multiple of 16, so row&7 == l16&7.
#define MEMBAR asm volatile("" ::: "memory")
#define BARR do { MEMBAR; __builtin_amdgcn_s_barrier(); MEMBAR; } while (0)
#define VMW(n) asm volatile("s_waitcnt vmcnt(" #n ")" ::: "memory")
#define GLDS(SRC, DST) __builtin_amdgcn_global_load_lds( \
    (const __attribute__((address_space(1))) void*)(SRC), \
    (__attribute__((address_space(3))) void*)(DST), 16, 0, 0)

__global__ __launch_bounds__(512, 2) void k_gemm(const unsigned short* __restrict__ A,
                                                 const unsigned short* __restrict__ Bb,
                                                 float* __restrict__ C) {
  __shared__ __align__(16) unsigned short lA[32768];   // 64 KiB
  __shared__ __align__(16) unsigned short lB[32768];   // 64 KiB
  const int tid  = threadIdx.x;
  const int wid  = tid >> 6, lane = tid & 63;
  const int wr   = wid >> 2, wc = wid & 3;             // 2x4 wave grid
  const int quad = lane >> 4, l16 = lane & 15;
  const int sx   = l16 & 7;                            // read-side swizzle key
  const int bh   = wc >> 1, br = (wc & 1) * 64;        // B half / row base for this wave
  const int bid  = blockIdx.x;
  const int wgid = (bid & 7) * 32 + (bid >> 3);        // XCD-chunked swizzle (256%8==0, bijective)
  const long m0 = (long)(wgid >> 2) * 256;
  const long n0 = (long)(wgid & 3) * 256;
  // stage-side: inverse-swizzled global source (same XOR involution)
  const int sgran = (tid & 7) ^ ((tid >> 3) & 7);
  const unsigned short* gA = A  + (m0 + (tid >> 3)) * K_ + sgran * 8;
  const unsigned short* gB = Bb + (n0 + (tid >> 3)) * K_ + sgran * 8;
  unsigned short* sAw = lA + wid * 512;                // wave-uniform LDS dest slice
  unsigned short* sBw = lB + wid * 512;

#define STG_A(d, hf, t) do { \
    GLDS(gA + ((hf) * 128) * K_ + (t) * 64,      sAw + (d) * 16384 + (hf) * 8192); \
    GLDS(gA + ((hf) * 128 + 64) * K_ + (t) * 64, sAw + (d) * 16384 + (hf) * 8192 + 4096); } while (0)
#define STG_B(d, hf, t) do { \
    GLDS(gB + ((hf) * 128) * K_ + (t) * 64,      sBw + (d) * 16384 + (hf) * 8192); \
    GLDS(gB + ((hf) * 128 + 64) * K_ + (t) * 64, sBw + (d) * 16384 + (hf) * 8192 + 4096); } while (0)

  f32x4 acc[8][4];
  #pragma unroll
  for (int i = 0; i < 8; i++)
    #pragma unroll
    for (int j = 0; j < 4; j++) acc[i][j] = f32x4{0.f, 0.f, 0.f, 0.f};

  frag8 aR[4][2];        // current ih-half A frags: [ii][ks]
  frag8 bR[2][2][2];     // both jh halves live:    [jh][jj][ks]

#define RD_A(d, ih) do { _Pragma("unroll") \
    for (int ii = 0; ii < 4; ii++) { \
      const unsigned short* rp = lA + (d) * 16384 + wr * 8192 + (((ih) * 4 + ii) * 16 + l16) * 64; \
      aR[ii][0] = *(const frag8*)(rp + (quad ^ sx) * 8); \
      aR[ii][1] = *(const frag8*)(rp + ((quad + 4) ^ sx) * 8); } } while (0)
#define RD_B(d, jh) do { _Pragma("unroll") \
    for (int jj = 0; jj < 2; jj++) { \
      const unsigned short* rp = lB + (d) * 16384 + bh * 8192 + (br + ((jh) * 2 + jj) * 16 + l16) * 64; \
      bR[jh][jj][0] = *(const frag8*)(rp + (quad ^ sx) * 8); \
      bR[jh][jj][1] = *(const frag8*)(rp + ((quad + 4) ^ sx) * 8); } } while (0)
#define MMQ(ih, jh) do { __builtin_amdgcn_s_setprio(1); _Pragma("unroll") \
    for (int ii = 0; ii < 4; ii++) { _Pragma("unroll") \
      for (int jj = 0; jj < 2; jj++) { \
        acc[(ih)*4+ii][(jh)*2+jj] = __builtin_amdgcn_mfma_f32_16x16x32_bf16(aR[ii][0], bR[jh][jj][0], acc[(ih)*4+ii][(jh)*2+jj], 0, 0, 0); \
        acc[(ih)*4+ii][(jh)*2+jj] = __builtin_amdgcn_mfma_f32_16x16x32_bf16(aR[ii][1], bR[jh][jj][1], acc[(ih)*4+ii][(jh)*2+jj], 0, 0, 0); } } \
    __builtin_amdgcn_s_setprio(0); } while (0)

  // prologue: tile0 all 4 halves + tile1 half A0 (5 halves = 10 loads); need tile0 -> vmcnt(2)
  STG_A(0, 0, 0); STG_A(0, 1, 0); STG_B(0, 0, 0); STG_B(0, 1, 0); STG_A(1, 0, 1);
  VMW(2); BARR;

  for (int it = 0; it < 7; ++it) {
    const int to = 2 * it + 1, te2 = 2 * it + 2, to2 = 2 * it + 3;
    RD_A(0, 0); RD_B(0, 0); STG_A(1, 1, to);  BARR; MMQ(0, 0);         BARR;  // p1
    RD_B(0, 1);             STG_B(1, 0, to);  BARR; MMQ(0, 1);         BARR;  // p2
    RD_A(0, 1);             STG_B(1, 1, to);  BARR; MMQ(1, 1);         BARR;  // p3
                            STG_A(0, 0, te2); BARR; MMQ(1, 0); VMW(2); BARR;  // p4
    RD_A(1, 0); RD_B(1, 0); STG_A(0, 1, te2); BARR; MMQ(0, 0);         BARR;  // p5
    RD_B(1, 1);             STG_B(0, 0, te2); BARR; MMQ(0, 1);         BARR;  // p6
    RD_A(1, 1);             STG_B(0, 1, te2); BARR; MMQ(1, 1);         BARR;  // p7
                            STG_A(1, 0, to2); BARR; MMQ(1, 0); VMW(2); BARR;  // p8
  }
  // peeled final iteration (tiles 14, 15): p1-3 still stage tile15's remaining halves
  RD_A(0, 0); RD_B(0, 0); STG_A(1, 1, 15); BARR; MMQ(0, 0);         BARR;
  RD_B(0, 1);             STG_B(1, 0, 15); BARR; MMQ(0, 1);         BARR;
  RD_A(0, 1);             STG_B(1, 1, 15); BARR; MMQ(1, 1);         BARR;
                                           BARR; MMQ(1, 0); VMW(0); BARR;
  RD_A(1, 0); RD_B(1, 0);                  BARR; MMQ(0, 0);         BARR;
  RD_B(1, 1);                              BARR; MMQ(0, 1);         BARR;
  RD_A(1, 1);                              BARR; MMQ(1, 1);         BARR;
  MMQ(1, 0);

  // epilogue: C/D layout col=l16, row=quad*4+r (m89-verified mapping)
  #pragma unroll
  for (int i = 0; i < 8; i++)
    #pragma unroll
    for (int j = 0; j < 4; j++) {
      const long r0 = m0 + wr * 128 + i * 16 + quad * 4;
      const long c0 = n0 + wc * 64 + j * 16 + l16;
      #pragma unroll
      for (int r = 0; r < 4; r++)
        C[(r0 + r) * N_ + c0] = acc[i][j][r];
    }
}

// ---------------- scan phase 1: per-segment local end-states (R1-verified) ----------------
__global__ __launch_bounds__(256) void k_seg_ends(const float* __restrict__ u,
                                                  const float* __restrict__ a_sig,
                                                  float* __restrict__ E) {
  int g = blockIdx.x * 256 + threadIdx.x;   // 0 .. NVC*SEG-1 = 131071
  int vc = g & (NVC - 1);                   // 0..2047 (vec4 channel)
  int s  = g >> 11;                         // segment 0..63
  int b  = vc >> 8;                         // batch
  int h4 = (vc & 255) * 4;                  // first of 4 h-channels
  float4 a = *reinterpret_cast<const float4*>(a_sig + h4);
  const float* base = u + (long)b * T_ * H_ + (long)s * TSEG * H_ + h4;
  float4 e = {0.f, 0.f, 0.f, 0.f};
  #pragma unroll
  for (int t0 = 0; t0 < TSEG; t0 += 8) {
    float4 v[8];
    #pragma unroll
    for (int j = 0; j < 8; j++)
      v[j] = *reinterpret_cast<const float4*>(base + (long)(t0 + j) * H_);
    #pragma unroll
    for (int j = 0; j < 8; j++)
      e = fma4(e, a, v[j]);
  }
  *reinterpret_cast<float4*>(E + (long)g * 4) = e;
}

// ---------------- scan phase 2: carry chain across segments (R1-verified, in-place on EC) ----------------
__global__ __launch_bounds__(256) void k_carries(float* __restrict__ EC,
                                                 const float* __restrict__ h0,
                                                 const float* __restrict__ a_sig) {
  int c = blockIdx.x * 256 + threadIdx.x;   // 0..8191
  if (c >= NCH) return;
  float a = a_sig[c & (H_ - 1)];
  float aL = a;
  #pragma unroll
  for (int i = 0; i < 5; i++) aL *= aL;     // a^32 = a^TSEG
  float carry = h0[c];
  #pragma unroll
  for (int s0 = 0; s0 < SEG; s0 += 8) {
    float e[8];
    #pragma unroll
    for (int j = 0; j < 8; j++) e[j] = EC[(long)(s0 + j) * NCH + c];
    #pragma unroll
    for (int j = 0; j < 8; j++) {
      EC[(long)(s0 + j) * NCH + c] = carry;
      carry = fmaf(aL, carry, e[j]);
    }
  }
}

// ---------------- scan phase 3: final scan with carry-in, in-place (R1-verified) ----------------
__global__ __launch_bounds__(256) void k_scan(float* __restrict__ u,
                                              const float* __restrict__ Cc,
                                              const float* __restrict__ a_sig) {
  int g = blockIdx.x * 256 + threadIdx.x;
  int vc = g & (NVC - 1);
  int s  = g >> 11;
  int b  = vc >> 8;
  int h4 = (vc & 255) * 4;
  float4 a = *reinterpret_cast<const float4*>(a_sig + h4);
  float4 hs = *reinterpret_cast<const float4*>(Cc + (long)g * 4);
  float* base = u + (long)b * T_ * H_ + (long)s * TSEG * H_ + h4;

  float4 v0[8], v1[8];
  #pragma unroll
  for (int j = 0; j < 8; j++)
    v0[j] = *reinterpret_cast<const float4*>(base + (long)j * H_);

  #pragma unroll
  for (int t0 = 0; t0 < TSEG; t0 += 8) {
    const bool odd = (t0 >> 3) & 1;          // compile-time after full unroll
    float4* cur = odd ? v1 : v0;
    float4* nxt = odd ? v0 : v1;
    if (t0 + 8 < TSEG) {
      #pragma unroll
      for (int j = 0; j < 8; j++)
        nxt[j] = *reinterpret_cast<const float4*>(base + (long)(t0 + 8 + j) * H_);
    }
    #pragma unroll
    for (int j = 0; j < 8; j++) {
      hs = fma4(hs, a, cur[j]);
      cur[j] = hs;
    }
    #pragma unroll
    for (int j = 0; j < 8; j++)
      *reinterpret_cast<float4*>(base + (long)(t0 + j) * H_) = cur[j];
  }
}

extern "C" void kernel_launch(void* const* d_in, const int* in_sizes, int n_in,
                              void* d_out, int out_size, void* d_ws, size_t ws_size,
                              hipStream_t stream) {
  const float* x    = (const float*)d_in[0];   // [8,2048,1024]
  const float* rawa = (const float*)d_in[1];   // [1024]
  const float* Bm   = (const float*)d_in[2];   // [1024,1024]
  const float* h0   = (const float*)d_in[3];   // [8,1024]
  float* u = (float*)d_out;                    // u then y, in place

  // Workspace layout (R1-verified footprint):
  // xb 32 MiB | Bb 2 MiB | a_sig 4 KiB | EC 2 MiB
  char* w = (char*)d_ws;
  unsigned short* xb = (unsigned short*)w;                               // 32 MiB
  unsigned short* Bb = (unsigned short*)(w + 33554432);                  // 2 MiB
  float* a_sig = (float*)(w + 33554432 + 2097152);                       // 4 KiB
  float* EC    = (float*)(w + 33554432 + 2097152 + 4096);                // 2 MiB

  hipLaunchKernelGGL(k_convert, dim3(17409), dim3(256), 0, stream, x, Bm, rawa, xb, Bb, a_sig);
  hipLaunchKernelGGL(k_gemm, dim3(256), dim3(512), 0, stream, xb, Bb, u);
  hipLaunchKernelGGL(k_seg_ends, dim3(NVC * SEG / 256), dim3(256), 0, stream, u, a_sig, EC);
  hipLaunchKernelGGL(k_carries, dim3(NCH / 256), dim3(256), 0, stream, EC, h0, a_sig);
  hipLaunchKernelGGL(k_scan, dim3(NVC * SEG / 256), dim3(256), 0, stream, u, EC, a_sig);
}

// Round 5
// 183.611 us; speedup vs baseline: 1.1002x; 1.0095x over previous
//
#include <hip/hip_runtime.h>
#include <hip/hip_bf16.h>

using bf16 = __hip_bfloat16;
typedef __attribute__((ext_vector_type(8))) short frag8;   // 8 bf16 (4 VGPRs)
typedef __attribute__((ext_vector_type(4))) float f32x4;   // 4 fp32 acc

constexpr int   H_   = 1024;               // N_EMBD
constexpr int   B_   = 8;                  // BATCH
constexpr int   T_   = 2048;
constexpr int   K_   = H_;
constexpr int   N_   = H_;
constexpr long  M_   = (long)B_ * T_;      // 16384
constexpr int   SEG  = 64;                 // segments per sequence
constexpr int   TSEG = T_ / SEG;           // 32
constexpr int   NCH  = B_ * H_;            // 8192 channels
constexpr int   NVC  = NCH / 4;            // 2048 vec4-channels

__device__ __forceinline__ unsigned short f2bf(float f) {
  bf16 b = __float2bfloat16(f);
  return *reinterpret_cast<unsigned short*>(&b);
}

__device__ __forceinline__ float4 fma4(float4 h, float4 a, float4 v) {
  float4 r;
  r.x = fmaf(h.x, a.x, v.x);
  r.y = fmaf(h.y, a.y, v.y);
  r.z = fmaf(h.z, a.z, v.z);
  r.w = fmaf(h.w, a.w, v.w);
  return r;
}

// ---------------- fp32 -> bf16 convert (x then B) + fused sigmoid (R1-verified) ----------------
__global__ __launch_bounds__(256) void k_convert(const float* __restrict__ x,
                                                 const float* __restrict__ Bm,
                                                 const float* __restrict__ raw,
                                                 unsigned short* __restrict__ xb,
                                                 unsigned short* __restrict__ Bb,
                                                 float* __restrict__ a_sig) {
  const long NX4 = (M_ * K_) / 4;             // 4194304
  const long NB4 = ((long)N_ * K_) / 4;       // 262144
  long t = (long)blockIdx.x * 256 + threadIdx.x;
  const float* src; unsigned short* dst;
  if (t < NX4) { src = x; dst = xb; }
  else if (t < NX4 + NB4) { t -= NX4; src = Bm; dst = Bb; }
  else {
    long q = t - NX4 - NB4;
    if (q >= H_ / 4) return;
    float4 v = *reinterpret_cast<const float4*>(raw + q * 4);
    float4 o;
    o.x = 1.0f / (1.0f + expf(-v.x));
    o.y = 1.0f / (1.0f + expf(-v.y));
    o.z = 1.0f / (1.0f + expf(-v.z));
    o.w = 1.0f / (1.0f + expf(-v.w));
    *reinterpret_cast<float4*>(a_sig + q * 4) = o;
    return;
  }
  long i = t * 4;
  float4 v = *reinterpret_cast<const float4*>(src + i);
  short4 o;
  o.x = (short)f2bf(v.x);
  o.y = (short)f2bf(v.y);
  o.z = (short)f2bf(v.z);
  o.w = (short)f2bf(v.w);
  *reinterpret_cast<short4*>(dst + i) = o;
}

// ---------------- bf16 GEMM: 256x256 tile, BK=64, 8-wave, 8-phase counted-vmcnt pipeline ----------------
// R4: T2 XOR swizzle (linear LDS dest, inverse-swizzled global source, swizzled reads). Conflicts = 0.
// R5: ONE barrier per phase (was 2). Hazard proof: region staged at phase q was
// last read at q-3 (tightest: dbuf1-A-h1 read at prev-p7, overwritten at p1);
// any wave at STG(q) has passed BARR(q-1), which transitively guarantees every
// wave's lgkmcnt(0)-completed reads through phase q-2. vmcnt publish (VMW)
// moved BEFORE the barrier at p4/p8 so all waves' staging is visible before
// the consuming RD. Effect: phase q+1's ds_reads issue right after each wave's
// own MFMAs -> LDS pipe overlaps other waves' MFMA instead of strict
// alternation (read-burst / MFMA-burst lockstep was the 28%-MfmaUtil cap).
#define MEMBAR asm volatile("" ::: "memory")
#define BARR do { MEMBAR; __builtin_amdgcn_s_barrier(); MEMBAR; } while (0)
#define VMW(n) asm volatile("s_waitcnt vmcnt(" #n ")" ::: "memory")
#define GLDS(SRC, DST) __builtin_amdgcn_global_load_lds( \
    (const __attribute__((address_space(1))) void*)(SRC), \
    (__attribute__((address_space(3))) void*)(DST), 16, 0, 0)

__global__ __launch_bounds__(512, 2) void k_gemm(const unsigned short* __restrict__ A,
                                                 const unsigned short* __restrict__ Bb,
                                                 float* __restrict__ C) {
  __shared__ __align__(16) unsigned short lA[32768];   // 64 KiB
  __shared__ __align__(16) unsigned short lB[32768];   // 64 KiB
  const int tid  = threadIdx.x;
  const int wid  = tid >> 6, lane = tid & 63;
  const int wr   = wid >> 2, wc = wid & 3;             // 2x4 wave grid
  const int quad = lane >> 4, l16 = lane & 15;
  const int sx   = l16 & 7;                            // read-side swizzle key
  const int bh   = wc >> 1, br = (wc & 1) * 64;        // B half / row base for this wave
  const int bid  = blockIdx.x;
  const int wgid = (bid & 7) * 32 + (bid >> 3);        // XCD-chunked swizzle (256%8==0, bijective)
  const long m0 = (long)(wgid >> 2) * 256;
  const long n0 = (long)(wgid & 3) * 256;
  // stage-side: inverse-swizzled global source (same XOR involution)
  const int sgran = (tid & 7) ^ ((tid >> 3) & 7);
  const unsigned short* gA = A  + (m0 + (tid >> 3)) * K_ + sgran * 8;
  const unsigned short* gB = Bb + (n0 + (tid >> 3)) * K_ + sgran * 8;
  unsigned short* sAw = lA + wid * 512;                // wave-uniform LDS dest slice
  unsigned short* sBw = lB + wid * 512;

#define STG_A(d, hf, t) do { \
    GLDS(gA + ((hf) * 128) * K_ + (t) * 64,      sAw + (d) * 16384 + (hf) * 8192); \
    GLDS(gA + ((hf) * 128 + 64) * K_ + (t) * 64, sAw + (d) * 16384 + (hf) * 8192 + 4096); } while (0)
#define STG_B(d, hf, t) do { \
    GLDS(gB + ((hf) * 128) * K_ + (t) * 64,      sBw + (d) * 16384 + (hf) * 8192); \
    GLDS(gB + ((hf) * 128 + 64) * K_ + (t) * 64, sBw + (d) * 16384 + (hf) * 8192 + 4096); } while (0)

  f32x4 acc[8][4];
  #pragma unroll
  for (int i = 0; i < 8; i++)
    #pragma unroll
    for (int j = 0; j < 4; j++) acc[i][j] = f32x4{0.f, 0.f, 0.f, 0.f};

  frag8 aR[4][2];        // current ih-half A frags: [ii][ks]
  frag8 bR[2][2][2];     // both jh halves live:    [jh][jj][ks]

#define RD_A(d, ih) do { _Pragma("unroll") \
    for (int ii = 0; ii < 4; ii++) { \
      const unsigned short* rp = lA + (d) * 16384 + wr * 8192 + (((ih) * 4 + ii) * 16 + l16) * 64; \
      aR[ii][0] = *(const frag8*)(rp + (quad ^ sx) * 8); \
      aR[ii][1] = *(const frag8*)(rp + ((quad + 4) ^ sx) * 8); } } while (0)
#define RD_B(d, jh) do { _Pragma("unroll") \
    for (int jj = 0; jj < 2; jj++) { \
      const unsigned short* rp = lB + (d) * 16384 + bh * 8192 + (br + ((jh) * 2 + jj) * 16 + l16) * 64; \
      bR[jh][jj][0] = *(const frag8*)(rp + (quad ^ sx) * 8); \
      bR[jh][jj][1] = *(const frag8*)(rp + ((quad + 4) ^ sx) * 8); } } while (0)
#define MMQ(ih, jh) do { __builtin_amdgcn_s_setprio(1); _Pragma("unroll") \
    for (int ii = 0; ii < 4; ii++) { _Pragma("unroll") \
      for (int jj = 0; jj < 2; jj++) { \
        acc[(ih)*4+ii][(jh)*2+jj] = __builtin_amdgcn_mfma_f32_16x16x32_bf16(aR[ii][0], bR[jh][jj][0], acc[(ih)*4+ii][(jh)*2+jj], 0, 0, 0); \
        acc[(ih)*4+ii][(jh)*2+jj] = __builtin_amdgcn_mfma_f32_16x16x32_bf16(aR[ii][1], bR[jh][jj][1], acc[(ih)*4+ii][(jh)*2+jj], 0, 0, 0); } } \
    __builtin_amdgcn_s_setprio(0); } while (0)

  // prologue: tile0 all 4 halves + tile1 half A0 (5 halves = 10 loads); need tile0 -> vmcnt(2)
  STG_A(0, 0, 0); STG_A(0, 1, 0); STG_B(0, 0, 0); STG_B(0, 1, 0); STG_A(1, 0, 1);
  VMW(2); BARR;

  for (int it = 0; it < 7; ++it) {
    const int to = 2 * it + 1, te2 = 2 * it + 2, to2 = 2 * it + 3;
    RD_A(0, 0); RD_B(0, 0); STG_A(1, 1, to);          BARR; MMQ(0, 0);  // p1
    RD_B(0, 1);             STG_B(1, 0, to);          BARR; MMQ(0, 1);  // p2
    RD_A(0, 1);             STG_B(1, 1, to);          BARR; MMQ(1, 1);  // p3
                            STG_A(0, 0, te2); VMW(2); BARR; MMQ(1, 0);  // p4
    RD_A(1, 0); RD_B(1, 0); STG_A(0, 1, te2);         BARR; MMQ(0, 0);  // p5
    RD_B(1, 1);             STG_B(0, 0, te2);         BARR; MMQ(0, 1);  // p6
    RD_A(1, 1);             STG_B(0, 1, te2);         BARR; MMQ(1, 1);  // p7
                            STG_A(1, 0, to2); VMW(2); BARR; MMQ(1, 0);  // p8
  }
  // peeled final iteration (tiles 14, 15): p1-3 still stage tile15's remaining halves
  RD_A(0, 0); RD_B(0, 0); STG_A(1, 1, 15);         BARR; MMQ(0, 0);
  RD_B(0, 1);             STG_B(1, 0, 15);         BARR; MMQ(0, 1);
  RD_A(0, 1);             STG_B(1, 1, 15);         BARR; MMQ(1, 1);
                                           VMW(0); BARR; MMQ(1, 0);
  RD_A(1, 0); RD_B(1, 0);                          BARR; MMQ(0, 0);
  RD_B(1, 1);                                      BARR; MMQ(0, 1);
  RD_A(1, 1);                                      BARR; MMQ(1, 1);
  MMQ(1, 0);

  // epilogue: C/D layout col=l16, row=quad*4+r (m89-verified mapping)
  #pragma unroll
  for (int i = 0; i < 8; i++)
    #pragma unroll
    for (int j = 0; j < 4; j++) {
      const long r0 = m0 + wr * 128 + i * 16 + quad * 4;
      const long c0 = n0 + wc * 64 + j * 16 + l16;
      #pragma unroll
      for (int r = 0; r < 4; r++)
        C[(r0 + r) * N_ + c0] = acc[i][j][r];
    }
}

// ---------------- scan phase 1: per-segment local end-states (R1-verified) ----------------
__global__ __launch_bounds__(256) void k_seg_ends(const float* __restrict__ u,
                                                  const float* __restrict__ a_sig,
                                                  float* __restrict__ E) {
  int g = blockIdx.x * 256 + threadIdx.x;   // 0 .. NVC*SEG-1 = 131071
  int vc = g & (NVC - 1);                   // 0..2047 (vec4 channel)
  int s  = g >> 11;                         // segment 0..63
  int b  = vc >> 8;                         // batch
  int h4 = (vc & 255) * 4;                  // first of 4 h-channels
  float4 a = *reinterpret_cast<const float4*>(a_sig + h4);
  const float* base = u + (long)b * T_ * H_ + (long)s * TSEG * H_ + h4;
  float4 e = {0.f, 0.f, 0.f, 0.f};
  #pragma unroll
  for (int t0 = 0; t0 < TSEG; t0 += 8) {
    float4 v[8];
    #pragma unroll
    for (int j = 0; j < 8; j++)
      v[j] = *reinterpret_cast<const float4*>(base + (long)(t0 + j) * H_);
    #pragma unroll
    for (int j = 0; j < 8; j++)
      e = fma4(e, a, v[j]);
  }
  *reinterpret_cast<float4*>(E + (long)g * 4) = e;
}

// ---------------- scan phase 2: carry chain across segments (R1-verified, in-place on EC) ----------------
__global__ __launch_bounds__(256) void k_carries(float* __restrict__ EC,
                                                 const float* __restrict__ h0,
                                                 const float* __restrict__ a_sig) {
  int c = blockIdx.x * 256 + threadIdx.x;   // 0..8191
  if (c >= NCH) return;
  float a = a_sig[c & (H_ - 1)];
  float aL = a;
  #pragma unroll
  for (int i = 0; i < 5; i++) aL *= aL;     // a^32 = a^TSEG
  float carry = h0[c];
  #pragma unroll
  for (int s0 = 0; s0 < SEG; s0 += 8) {
    float e[8];
    #pragma unroll
    for (int j = 0; j < 8; j++) e[j] = EC[(long)(s0 + j) * NCH + c];
    #pragma unroll
    for (int j = 0; j < 8; j++) {
      EC[(long)(s0 + j) * NCH + c] = carry;
      carry = fmaf(aL, carry, e[j]);
    }
  }
}

// ---------------- scan phase 3: final scan with carry-in, in-place (R1-verified) ----------------
__global__ __launch_bounds__(256) void k_scan(float* __restrict__ u,
                                              const float* __restrict__ Cc,
                                              const float* __restrict__ a_sig) {
  int g = blockIdx.x * 256 + threadIdx.x;
  int vc = g & (NVC - 1);
  int s  = g >> 11;
  int b  = vc >> 8;
  int h4 = (vc & 255) * 4;
  float4 a = *reinterpret_cast<const float4*>(a_sig + h4);
  float4 hs = *reinterpret_cast<const float4*>(Cc + (long)g * 4);
  float* base = u + (long)b * T_ * H_ + (long)s * TSEG * H_ + h4;

  float4 v0[8], v1[8];
  #pragma unroll
  for (int j = 0; j < 8; j++)
    v0[j] = *reinterpret_cast<const float4*>(base + (long)j * H_);

  #pragma unroll
  for (int t0 = 0; t0 < TSEG; t0 += 8) {
    const bool odd = (t0 >> 3) & 1;          // compile-time after full unroll
    float4* cur = odd ? v1 : v0;
    float4* nxt = odd ? v0 : v1;
    if (t0 + 8 < TSEG) {
      #pragma unroll
      for (int j = 0; j < 8; j++)
        nxt[j] = *reinterpret_cast<const float4*>(base + (long)(t0 + 8 + j) * H_);
    }
    #pragma unroll
    for (int j = 0; j < 8; j++) {
      hs = fma4(hs, a, cur[j]);
      cur[j] = hs;
    }
    #pragma unroll
    for (int j = 0; j < 8; j++)
      *reinterpret_cast<float4*>(base + (long)(t0 + j) * H_) = cur[j];
  }
}

extern "C" void kernel_launch(void* const* d_in, const int* in_sizes, int n_in,
                              void* d_out, int out_size, void* d_ws, size_t ws_size,
                              hipStream_t stream) {
  const float* x    = (const float*)d_in[0];   // [8,2048,1024]
  const float* rawa = (const float*)d_in[1];   // [1024]
  const float* Bm   = (const float*)d_in[2];   // [1024,1024]
  const float* h0   = (const float*)d_in[3];   // [8,1024]
  float* u = (float*)d_out;                    // u then y, in place

  // Workspace layout (R1-verified footprint):
  // xb 32 MiB | Bb 2 MiB | a_sig 4 KiB | EC 2 MiB
  char* w = (char*)d_ws;
  unsigned short* xb = (unsigned short*)w;                               // 32 MiB
  unsigned short* Bb = (unsigned short*)(w + 33554432);                  // 2 MiB
  float* a_sig = (float*)(w + 33554432 + 2097152);                       // 4 KiB
  float* EC    = (float*)(w + 33554432 + 2097152 + 4096);                // 2 MiB

  hipLaunchKernelGGL(k_convert, dim3(17409), dim3(256), 0, stream, x, Bm, rawa, xb, Bb, a_sig);
  hipLaunchKernelGGL(k_gemm, dim3(256), dim3(512), 0, stream, xb, Bb, u);
  hipLaunchKernelGGL(k_seg_ends, dim3(NVC * SEG / 256), dim3(256), 0, stream, u, a_sig, EC);
  hipLaunchKernelGGL(k_carries, dim3(NCH / 256), dim3(256), 0, stream, EC, h0, a_sig);
  hipLaunchKernelGGL(k_scan, dim3(NVC * SEG / 256), dim3(256), 0, stream, u, EC, a_sig);
}

// Round 7
// 181.656 us; speedup vs baseline: 1.1120x; 1.0108x over previous
//
#include <hip/hip_runtime.h>
#include <hip/hip_bf16.h>

using bf16 = __hip_bfloat16;
typedef __attribute__((ext_vector_type(8))) short frag8;   // 8 bf16 (4 VGPRs)
typedef __attribute__((ext_vector_type(4))) float f32x4;   // 4 fp32 acc

constexpr int   H_   = 1024;               // N_EMBD
constexpr int   B_   = 8;                  // BATCH
constexpr int   T_   = 2048;
constexpr int   K_   = H_;
constexpr int   N_   = H_;
constexpr long  M_   = (long)B_ * T_;      // 16384
constexpr int   SEG  = 64;                 // segments per sequence
constexpr int   TSEG = T_ / SEG;           // 32
constexpr int   NCH  = B_ * H_;            // 8192 channels
constexpr int   NVC  = NCH / 4;            // 2048 vec4-channels

__device__ __forceinline__ unsigned short f2bf(float f) {
  bf16 b = __float2bfloat16(f);
  return *reinterpret_cast<unsigned short*>(&b);
}

__device__ __forceinline__ float4 fma4(float4 h, float4 a, float4 v) {
  float4 r;
  r.x = fmaf(h.x, a.x, v.x);
  r.y = fmaf(h.y, a.y, v.y);
  r.z = fmaf(h.z, a.z, v.z);
  r.w = fmaf(h.w, a.w, v.w);
  return r;
}

// ---------------- fp32 -> bf16 convert (x then B) + fused sigmoid (R1-verified) ----------------
__global__ __launch_bounds__(256) void k_convert(const float* __restrict__ x,
                                                 const float* __restrict__ Bm,
                                                 const float* __restrict__ raw,
                                                 unsigned short* __restrict__ xb,
                                                 unsigned short* __restrict__ Bb,
                                                 float* __restrict__ a_sig) {
  const long NX4 = (M_ * K_) / 4;             // 4194304
  const long NB4 = ((long)N_ * K_) / 4;       // 262144
  long t = (long)blockIdx.x * 256 + threadIdx.x;
  const float* src; unsigned short* dst;
  if (t < NX4) { src = x; dst = xb; }
  else if (t < NX4 + NB4) { t -= NX4; src = Bm; dst = Bb; }
  else {
    long q = t - NX4 - NB4;
    if (q >= H_ / 4) return;
    float4 v = *reinterpret_cast<const float4*>(raw + q * 4);
    float4 o;
    o.x = 1.0f / (1.0f + expf(-v.x));
    o.y = 1.0f / (1.0f + expf(-v.y));
    o.z = 1.0f / (1.0f + expf(-v.z));
    o.w = 1.0f / (1.0f + expf(-v.w));
    *reinterpret_cast<float4*>(a_sig + q * 4) = o;
    return;
  }
  long i = t * 4;
  float4 v = *reinterpret_cast<const float4*>(src + i);
  short4 o;
  o.x = (short)f2bf(v.x);
  o.y = (short)f2bf(v.y);
  o.z = (short)f2bf(v.z);
  o.w = (short)f2bf(v.w);
  *reinterpret_cast<short4*>(dst + i) = o;
}

// ---------------- bf16 GEMM: 256x256 tile, BK=64, 8-wave, 8-phase counted-vmcnt pipeline ----------------
// R4: T2 XOR swizzle (linear LDS dest, inverse-swizzled global source, swizzled reads). Conflicts = 0.
// R5: ONE barrier per phase. R7: exact R5 revert (R6's rolling prefetch NaN'd; unattributed).
#define MEMBAR asm volatile("" ::: "memory")
#define BARR do { MEMBAR; __builtin_amdgcn_s_barrier(); MEMBAR; } while (0)
#define VMW(n) asm volatile("s_waitcnt vmcnt(" #n ")" ::: "memory")
#define GLDS(SRC, DST) __builtin_amdgcn_global_load_lds( \
    (const __attribute__((address_space(1))) void*)(SRC), \
    (__attribute__((address_space(3))) void*)(DST), 16, 0, 0)

__global__ __launch_bounds__(512, 2) void k_gemm(const unsigned short* __restrict__ A,
                                                 const unsigned short* __restrict__ Bb,
                                                 float* __restrict__ C) {
  __shared__ __align__(16) unsigned short lA[32768];   // 64 KiB
  __shared__ __align__(16) unsigned short lB[32768];   // 64 KiB
  const int tid  = threadIdx.x;
  const int wid  = tid >> 6, lane = tid & 63;
  const int wr   = wid >> 2, wc = wid & 3;             // 2x4 wave grid
  const int quad = lane >> 4, l16 = lane & 15;
  const int sx   = l16 & 7;                            // read-side swizzle key
  const int bh   = wc >> 1, br = (wc & 1) * 64;        // B half / row base for this wave
  const int bid  = blockIdx.x;
  const int wgid = (bid & 7) * 32 + (bid >> 3);        // XCD-chunked swizzle (256%8==0, bijective)
  const long m0 = (long)(wgid >> 2) * 256;
  const long n0 = (long)(wgid & 3) * 256;
  // stage-side: inverse-swizzled global source (same XOR involution)
  const int sgran = (tid & 7) ^ ((tid >> 3) & 7);
  const unsigned short* gA = A  + (m0 + (tid >> 3)) * K_ + sgran * 8;
  const unsigned short* gB = Bb + (n0 + (tid >> 3)) * K_ + sgran * 8;
  unsigned short* sAw = lA + wid * 512;                // wave-uniform LDS dest slice
  unsigned short* sBw = lB + wid * 512;

#define STG_A(d, hf, t) do { \
    GLDS(gA + ((hf) * 128) * K_ + (t) * 64,      sAw + (d) * 16384 + (hf) * 8192); \
    GLDS(gA + ((hf) * 128 + 64) * K_ + (t) * 64, sAw + (d) * 16384 + (hf) * 8192 + 4096); } while (0)
#define STG_B(d, hf, t) do { \
    GLDS(gB + ((hf) * 128) * K_ + (t) * 64,      sBw + (d) * 16384 + (hf) * 8192); \
    GLDS(gB + ((hf) * 128 + 64) * K_ + (t) * 64, sBw + (d) * 16384 + (hf) * 8192 + 4096); } while (0)

  f32x4 acc[8][4];
  #pragma unroll
  for (int i = 0; i < 8; i++)
    #pragma unroll
    for (int j = 0; j < 4; j++) acc[i][j] = f32x4{0.f, 0.f, 0.f, 0.f};

  frag8 aR[4][2];        // current ih-half A frags: [ii][ks]
  frag8 bR[2][2][2];     // both jh halves live:    [jh][jj][ks]

#define RD_A(d, ih) do { _Pragma("unroll") \
    for (int ii = 0; ii < 4; ii++) { \
      const unsigned short* rp = lA + (d) * 16384 + wr * 8192 + (((ih) * 4 + ii) * 16 + l16) * 64; \
      aR[ii][0] = *(const frag8*)(rp + (quad ^ sx) * 8); \
      aR[ii][1] = *(const frag8*)(rp + ((quad + 4) ^ sx) * 8); } } while (0)
#define RD_B(d, jh) do { _Pragma("unroll") \
    for (int jj = 0; jj < 2; jj++) { \
      const unsigned short* rp = lB + (d) * 16384 + bh * 8192 + (br + ((jh) * 2 + jj) * 16 + l16) * 64; \
      bR[jh][jj][0] = *(const frag8*)(rp + (quad ^ sx) * 8); \
      bR[jh][jj][1] = *(const frag8*)(rp + ((quad + 4) ^ sx) * 8); } } while (0)
#define MMQ(ih, jh) do { __builtin_amdgcn_s_setprio(1); _Pragma("unroll") \
    for (int ii = 0; ii < 4; ii++) { _Pragma("unroll") \
      for (int jj = 0; jj < 2; jj++) { \
        acc[(ih)*4+ii][(jh)*2+jj] = __builtin_amdgcn_mfma_f32_16x16x32_bf16(aR[ii][0], bR[jh][jj][0], acc[(ih)*4+ii][(jh)*2+jj], 0, 0, 0); \
        acc[(ih)*4+ii][(jh)*2+jj] = __builtin_amdgcn_mfma_f32_16x16x32_bf16(aR[ii][1], bR[jh][jj][1], acc[(ih)*4+ii][(jh)*2+jj], 0, 0, 0); } } \
    __builtin_amdgcn_s_setprio(0); } while (0)

  // prologue: tile0 all 4 halves + tile1 half A0 (5 halves = 10 loads); need tile0 -> vmcnt(2)
  STG_A(0, 0, 0); STG_A(0, 1, 0); STG_B(0, 0, 0); STG_B(0, 1, 0); STG_A(1, 0, 1);
  VMW(2); BARR;

  for (int it = 0; it < 7; ++it) {
    const int to = 2 * it + 1, te2 = 2 * it + 2, to2 = 2 * it + 3;
    RD_A(0, 0); RD_B(0, 0); STG_A(1, 1, to);          BARR; MMQ(0, 0);  // p1
    RD_B(0, 1);             STG_B(1, 0, to);          BARR; MMQ(0, 1);  // p2
    RD_A(0, 1);             STG_B(1, 1, to);          BARR; MMQ(1, 1);  // p3
                            STG_A(0, 0, te2); VMW(2); BARR; MMQ(1, 0);  // p4
    RD_A(1, 0); RD_B(1, 0); STG_A(0, 1, te2);         BARR; MMQ(0, 0);  // p5
    RD_B(1, 1);             STG_B(0, 0, te2);         BARR; MMQ(0, 1);  // p6
    RD_A(1, 1);             STG_B(0, 1, te2);         BARR; MMQ(1, 1);  // p7
                            STG_A(1, 0, to2); VMW(2); BARR; MMQ(1, 0);  // p8
  }
  // peeled final iteration (tiles 14, 15): p1-3 still stage tile15's remaining halves
  RD_A(0, 0); RD_B(0, 0); STG_A(1, 1, 15);         BARR; MMQ(0, 0);
  RD_B(0, 1);             STG_B(1, 0, 15);         BARR; MMQ(0, 1);
  RD_A(0, 1);             STG_B(1, 1, 15);         BARR; MMQ(1, 1);
                                           VMW(0); BARR; MMQ(1, 0);
  RD_A(1, 0); RD_B(1, 0);                          BARR; MMQ(0, 0);
  RD_B(1, 1);                                      BARR; MMQ(0, 1);
  RD_A(1, 1);                                      BARR; MMQ(1, 1);
  MMQ(1, 0);

  // epilogue: C/D layout col=l16, row=quad*4+r (m89-verified mapping)
  #pragma unroll
  for (int i = 0; i < 8; i++)
    #pragma unroll
    for (int j = 0; j < 4; j++) {
      const long r0 = m0 + wr * 128 + i * 16 + quad * 4;
      const long c0 = n0 + wc * 64 + j * 16 + l16;
      #pragma unroll
      for (int r = 0; r < 4; r++)
        C[(r0 + r) * N_ + c0] = acc[i][j][r];
    }
}

// ---------------- scan phase 1: per-segment local end-states (R1-verified) ----------------
__global__ __launch_bounds__(256) void k_seg_ends(const float* __restrict__ u,
                                                  const float* __restrict__ a_sig,
                                                  float* __restrict__ E) {
  int g = blockIdx.x * 256 + threadIdx.x;   // 0 .. NVC*SEG-1 = 131071
  int vc = g & (NVC - 1);                   // 0..2047 (vec4 channel)
  int s  = g >> 11;                         // segment 0..63
  int b  = vc >> 8;                         // batch
  int h4 = (vc & 255) * 4;                  // first of 4 h-channels
  float4 a = *reinterpret_cast<const float4*>(a_sig + h4);
  const float* base = u + (long)b * T_ * H_ + (long)s * TSEG * H_ + h4;
  float4 e = {0.f, 0.f, 0.f, 0.f};
  #pragma unroll
  for (int t0 = 0; t0 < TSEG; t0 += 8) {
    float4 v[8];
    #pragma unroll
    for (int j = 0; j < 8; j++)
      v[j] = *reinterpret_cast<const float4*>(base + (long)(t0 + j) * H_);
    #pragma unroll
    for (int j = 0; j < 8; j++)
      e = fma4(e, a, v[j]);
  }
  *reinterpret_cast<float4*>(E + (long)g * 4) = e;
}

// ---------------- scan phase 2+3 fused: per-block Horner carry + final scan, in-place ----------------
// R7: k_carries folded in (only change vs R5 tail). Block-uniform s; carry into
// segment s = Horner over E[0..s-1] with ratio a^32, seeded by h0. Loads batched
// 8-deep (independent addresses) so the L2 latency chain is ~s/8 round trips,
// not s. Math identical to the verified k_carries recurrence.
__global__ __launch_bounds__(256) void k_scan(float* __restrict__ u,
                                              const float* __restrict__ E,
                                              const float* __restrict__ h0,
                                              const float* __restrict__ a_sig) {
  int g = blockIdx.x * 256 + threadIdx.x;
  int vc = g & (NVC - 1);
  int s  = g >> 11;
  int b  = vc >> 8;
  int h4 = (vc & 255) * 4;
  float4 a = *reinterpret_cast<const float4*>(a_sig + h4);
  float4 aL = a;
  #pragma unroll
  for (int i = 0; i < 5; i++) { aL.x *= aL.x; aL.y *= aL.y; aL.z *= aL.z; aL.w *= aL.w; } // a^32
  float4 hs = *reinterpret_cast<const float4*>(h0 + (long)vc * 4);
  int j = 0;
  for (; j + 8 <= s; j += 8) {
    float4 e[8];
    #pragma unroll
    for (int q = 0; q < 8; q++)
      e[q] = *reinterpret_cast<const float4*>(E + (long)(j + q) * NCH + (long)vc * 4);
    #pragma unroll
    for (int q = 0; q < 8; q++)
      hs = fma4(hs, aL, e[q]);
  }
  for (; j < s; ++j) {
    float4 e = *reinterpret_cast<const float4*>(E + (long)j * NCH + (long)vc * 4);
    hs = fma4(hs, aL, e);
  }

  float* base = u + (long)b * T_ * H_ + (long)s * TSEG * H_ + h4;

  float4 v0[8], v1[8];
  #pragma unroll
  for (int jj = 0; jj < 8; jj++)
    v0[jj] = *reinterpret_cast<const float4*>(base + (long)jj * H_);

  #pragma unroll
  for (int t0 = 0; t0 < TSEG; t0 += 8) {
    const bool odd = (t0 >> 3) & 1;          // compile-time after full unroll
    float4* cur = odd ? v1 : v0;
    float4* nxt = odd ? v0 : v1;
    if (t0 + 8 < TSEG) {
      #pragma unroll
      for (int jj = 0; jj < 8; jj++)
        nxt[jj] = *reinterpret_cast<const float4*>(base + (long)(t0 + 8 + jj) * H_);
    }
    #pragma unroll
    for (int jj = 0; jj < 8; jj++) {
      hs = fma4(hs, a, cur[jj]);
      cur[jj] = hs;
    }
    #pragma unroll
    for (int jj = 0; jj < 8; jj++)
      *reinterpret_cast<float4*>(base + (long)(t0 + jj) * H_) = cur[jj];
  }
}

extern "C" void kernel_launch(void* const* d_in, const int* in_sizes, int n_in,
                              void* d_out, int out_size, void* d_ws, size_t ws_size,
                              hipStream_t stream) {
  const float* x    = (const float*)d_in[0];   // [8,2048,1024]
  const float* rawa = (const float*)d_in[1];   // [1024]
  const float* Bm   = (const float*)d_in[2];   // [1024,1024]
  const float* h0   = (const float*)d_in[3];   // [8,1024]
  float* u = (float*)d_out;                    // u then y, in place

  // Workspace layout (R1-verified footprint):
  // xb 32 MiB | Bb 2 MiB | a_sig 4 KiB | E 2 MiB
  char* w = (char*)d_ws;
  unsigned short* xb = (unsigned short*)w;                               // 32 MiB
  unsigned short* Bb = (unsigned short*)(w + 33554432);                  // 2 MiB
  float* a_sig = (float*)(w + 33554432 + 2097152);                       // 4 KiB
  float* E     = (float*)(w + 33554432 + 2097152 + 4096);                // 2 MiB

  hipLaunchKernelGGL(k_convert, dim3(17409), dim3(256), 0, stream, x, Bm, rawa, xb, Bb, a_sig);
  hipLaunchKernelGGL(k_gemm, dim3(256), dim3(512), 0, stream, xb, Bb, u);
  hipLaunchKernelGGL(k_seg_ends, dim3(NVC * SEG / 256), dim3(256), 0, stream, u, a_sig, E);
  hipLaunchKernelGGL(k_scan, dim3(NVC * SEG / 256), dim3(256), 0, stream, u, E, h0, a_sig);
}

// Round 8
// 172.272 us; speedup vs baseline: 1.1726x; 1.0545x over previous
//
#include <hip/hip_runtime.h>
#include <hip/hip_bf16.h>

using bf16 = __hip_bfloat16;
typedef __attribute__((ext_vector_type(8))) short frag8;   // 8 bf16 (4 VGPRs)
typedef __attribute__((ext_vector_type(4))) float f32x4;   // 4 fp32 acc

constexpr int   H_   = 1024;               // N_EMBD
constexpr int   B_   = 8;                  // BATCH
constexpr int   T_   = 2048;
constexpr int   K_   = H_;
constexpr int   N_   = H_;
constexpr long  M_   = (long)B_ * T_;      // 16384
constexpr int   SEG  = 64;                 // segments per sequence
constexpr int   TSEG = T_ / SEG;           // 32
constexpr int   NCH  = B_ * H_;            // 8192 channels
constexpr int   NVC  = NCH / 4;            // 2048 vec4-channels

__device__ __forceinline__ unsigned short f2bf(float f) {
  bf16 b = __float2bfloat16(f);
  return *reinterpret_cast<unsigned short*>(&b);
}

__device__ __forceinline__ float4 fma4(float4 h, float4 a, float4 v) {
  float4 r;
  r.x = fmaf(h.x, a.x, v.x);
  r.y = fmaf(h.y, a.y, v.y);
  r.z = fmaf(h.z, a.z, v.z);
  r.w = fmaf(h.w, a.w, v.w);
  return r;
}

// ---------------- fp32 -> bf16 convert (x then B) + fused sigmoid (R1-verified) ----------------
__global__ __launch_bounds__(256) void k_convert(const float* __restrict__ x,
                                                 const float* __restrict__ Bm,
                                                 const float* __restrict__ raw,
                                                 unsigned short* __restrict__ xb,
                                                 unsigned short* __restrict__ Bb,
                                                 float* __restrict__ a_sig) {
  const long NX4 = (M_ * K_) / 4;             // 4194304
  const long NB4 = ((long)N_ * K_) / 4;       // 262144
  long t = (long)blockIdx.x * 256 + threadIdx.x;
  const float* src; unsigned short* dst;
  if (t < NX4) { src = x; dst = xb; }
  else if (t < NX4 + NB4) { t -= NX4; src = Bm; dst = Bb; }
  else {
    long q = t - NX4 - NB4;
    if (q >= H_ / 4) return;
    float4 v = *reinterpret_cast<const float4*>(raw + q * 4);
    float4 o;
    o.x = 1.0f / (1.0f + expf(-v.x));
    o.y = 1.0f / (1.0f + expf(-v.y));
    o.z = 1.0f / (1.0f + expf(-v.z));
    o.w = 1.0f / (1.0f + expf(-v.w));
    *reinterpret_cast<float4*>(a_sig + q * 4) = o;
    return;
  }
  long i = t * 4;
  float4 v = *reinterpret_cast<const float4*>(src + i);
  short4 o;
  o.x = (short)f2bf(v.x);
  o.y = (short)f2bf(v.y);
  o.z = (short)f2bf(v.z);
  o.w = (short)f2bf(v.w);
  *reinterpret_cast<short4*>(dst + i) = o;
}

// ---------------- bf16 GEMM: 256x256 tile, BK=64, 8-wave, 8-phase counted-vmcnt pipeline ----------------
// R4: T2 XOR swizzle (conflicts 0). R5: one barrier/phase. R7: R5 loop (verified).
// R8: fused seg_ends in the epilogue. A 256-row m-tile = 8 whole segments of one
// batch; each 16-lane col-group holds a segment's 32 rows across its 4 quads
// (row = i*16+quad*4+r, i in {2s,2s+1}). e_s = sum_tau a^(31-tau) u_tau factors:
// per-thread Horner over r (weight a^(3-r)), cross-quad weight a^(4(7-4di-quad))
// from an a^4-power table, then shfl_xor(16)+shfl_xor(32) quad-reduce; quad==0
// lanes store E. n-tiles cover disjoint channels -> no races; k_seg_ends deleted.
#define MEMBAR asm volatile("" ::: "memory")
#define BARR do { MEMBAR; __builtin_amdgcn_s_barrier(); MEMBAR; } while (0)
#define VMW(n) asm volatile("s_waitcnt vmcnt(" #n ")" ::: "memory")
#define GLDS(SRC, DST) __builtin_amdgcn_global_load_lds( \
    (const __attribute__((address_space(1))) void*)(SRC), \
    (__attribute__((address_space(3))) void*)(DST), 16, 0, 0)

__global__ __launch_bounds__(512, 2) void k_gemm(const unsigned short* __restrict__ A,
                                                 const unsigned short* __restrict__ Bb,
                                                 float* __restrict__ C,
                                                 const float* __restrict__ a_sig,
                                                 float* __restrict__ E) {
  __shared__ __align__(16) unsigned short lA[32768];   // 64 KiB
  __shared__ __align__(16) unsigned short lB[32768];   // 64 KiB
  const int tid  = threadIdx.x;
  const int wid  = tid >> 6, lane = tid & 63;
  const int wr   = wid >> 2, wc = wid & 3;             // 2x4 wave grid
  const int quad = lane >> 4, l16 = lane & 15;
  const int sx   = l16 & 7;                            // read-side swizzle key
  const int bh   = wc >> 1, br = (wc & 1) * 64;        // B half / row base for this wave
  const int bid  = blockIdx.x;
  const int wgid = (bid & 7) * 32 + (bid >> 3);        // XCD-chunked swizzle (256%8==0, bijective)
  const long m0 = (long)(wgid >> 2) * 256;
  const long n0 = (long)(wgid & 3) * 256;
  // stage-side: inverse-swizzled global source (same XOR involution)
  const int sgran = (tid & 7) ^ ((tid >> 3) & 7);
  const unsigned short* gA = A  + (m0 + (tid >> 3)) * K_ + sgran * 8;
  const unsigned short* gB = Bb + (n0 + (tid >> 3)) * K_ + sgran * 8;
  unsigned short* sAw = lA + wid * 512;                // wave-uniform LDS dest slice
  unsigned short* sBw = lB + wid * 512;

#define STG_A(d, hf, t) do { \
    GLDS(gA + ((hf) * 128) * K_ + (t) * 64,      sAw + (d) * 16384 + (hf) * 8192); \
    GLDS(gA + ((hf) * 128 + 64) * K_ + (t) * 64, sAw + (d) * 16384 + (hf) * 8192 + 4096); } while (0)
#define STG_B(d, hf, t) do { \
    GLDS(gB + ((hf) * 128) * K_ + (t) * 64,      sBw + (d) * 16384 + (hf) * 8192); \
    GLDS(gB + ((hf) * 128 + 64) * K_ + (t) * 64, sBw + (d) * 16384 + (hf) * 8192 + 4096); } while (0)

  f32x4 acc[8][4];
  #pragma unroll
  for (int i = 0; i < 8; i++)
    #pragma unroll
    for (int j = 0; j < 4; j++) acc[i][j] = f32x4{0.f, 0.f, 0.f, 0.f};

  frag8 aR[4][2];        // current ih-half A frags: [ii][ks]
  frag8 bR[2][2][2];     // both jh halves live:    [jh][jj][ks]

#define RD_A(d, ih) do { _Pragma("unroll") \
    for (int ii = 0; ii < 4; ii++) { \
      const unsigned short* rp = lA + (d) * 16384 + wr * 8192 + (((ih) * 4 + ii) * 16 + l16) * 64; \
      aR[ii][0] = *(const frag8*)(rp + (quad ^ sx) * 8); \
      aR[ii][1] = *(const frag8*)(rp + ((quad + 4) ^ sx) * 8); } } while (0)
#define RD_B(d, jh) do { _Pragma("unroll") \
    for (int jj = 0; jj < 2; jj++) { \
      const unsigned short* rp = lB + (d) * 16384 + bh * 8192 + (br + ((jh) * 2 + jj) * 16 + l16) * 64; \
      bR[jh][jj][0] = *(const frag8*)(rp + (quad ^ sx) * 8); \
      bR[jh][jj][1] = *(const frag8*)(rp + ((quad + 4) ^ sx) * 8); } } while (0)
#define MMQ(ih, jh) do { __builtin_amdgcn_s_setprio(1); _Pragma("unroll") \
    for (int ii = 0; ii < 4; ii++) { _Pragma("unroll") \
      for (int jj = 0; jj < 2; jj++) { \
        acc[(ih)*4+ii][(jh)*2+jj] = __builtin_amdgcn_mfma_f32_16x16x32_bf16(aR[ii][0], bR[jh][jj][0], acc[(ih)*4+ii][(jh)*2+jj], 0, 0, 0); \
        acc[(ih)*4+ii][(jh)*2+jj] = __builtin_amdgcn_mfma_f32_16x16x32_bf16(aR[ii][1], bR[jh][jj][1], acc[(ih)*4+ii][(jh)*2+jj], 0, 0, 0); } } \
    __builtin_amdgcn_s_setprio(0); } while (0)

  // prologue: tile0 all 4 halves + tile1 half A0 (5 halves = 10 loads); need tile0 -> vmcnt(2)
  STG_A(0, 0, 0); STG_A(0, 1, 0); STG_B(0, 0, 0); STG_B(0, 1, 0); STG_A(1, 0, 1);
  VMW(2); BARR;

  for (int it = 0; it < 7; ++it) {
    const int to = 2 * it + 1, te2 = 2 * it + 2, to2 = 2 * it + 3;
    RD_A(0, 0); RD_B(0, 0); STG_A(1, 1, to);          BARR; MMQ(0, 0);  // p1
    RD_B(0, 1);             STG_B(1, 0, to);          BARR; MMQ(0, 1);  // p2
    RD_A(0, 1);             STG_B(1, 1, to);          BARR; MMQ(1, 1);  // p3
                            STG_A(0, 0, te2); VMW(2); BARR; MMQ(1, 0);  // p4
    RD_A(1, 0); RD_B(1, 0); STG_A(0, 1, te2);         BARR; MMQ(0, 0);  // p5
    RD_B(1, 1);             STG_B(0, 0, te2);         BARR; MMQ(0, 1);  // p6
    RD_A(1, 1);             STG_B(0, 1, te2);         BARR; MMQ(1, 1);  // p7
                            STG_A(1, 0, to2); VMW(2); BARR; MMQ(1, 0);  // p8
  }
  // peeled final iteration (tiles 14, 15): p1-3 still stage tile15's remaining halves
  RD_A(0, 0); RD_B(0, 0); STG_A(1, 1, 15);         BARR; MMQ(0, 0);
  RD_B(0, 1);             STG_B(1, 0, 15);         BARR; MMQ(0, 1);
  RD_A(0, 1);             STG_B(1, 1, 15);         BARR; MMQ(1, 1);
                                           VMW(0); BARR; MMQ(1, 0);
  RD_A(1, 0); RD_B(1, 0);                          BARR; MMQ(0, 0);
  RD_B(1, 1);                                      BARR; MMQ(0, 1);
  RD_A(1, 1);                                      BARR; MMQ(1, 1);
  MMQ(1, 0);

  // epilogue 1: C-store. C/D layout col=l16, row=quad*4+r (m89-verified mapping)
  #pragma unroll
  for (int i = 0; i < 8; i++)
    #pragma unroll
    for (int j = 0; j < 4; j++) {
      const long r0 = m0 + wr * 128 + i * 16 + quad * 4;
      const long c0 = n0 + wc * 64 + j * 16 + l16;
      #pragma unroll
      for (int r = 0; r < 4; r++)
        C[(r0 + r) * N_ + c0] = acc[i][j][r];
    }

  // epilogue 2 (R8): fused seg_ends. tau = 16*(i&1) + 4*quad + r within segment.
  {
    const int bb = (int)(m0 >> 11);           // batch
    const int sB = (int)((m0 & 2047) >> 5);   // first global segment of this tile
    #pragma unroll
    for (int j = 0; j < 4; j++) {
      const int c0 = (int)(n0) + wc * 64 + j * 16 + l16;   // channel h (0..1023)
      const float a  = a_sig[c0];
      const float a2 = a * a, a4 = a2 * a2;
      float p4[8];
      p4[0] = 1.f;
      #pragma unroll
      for (int k = 1; k < 8; k++) p4[k] = p4[k - 1] * a4;
      #pragma unroll
      for (int sp = 0; sp < 4; sp++) {        // segment pair = i>>1
        const f32x4 v = acc[sp * 2][j];       // di = 0 rows
        const f32x4 w = acc[sp * 2 + 1][j];   // di = 1 rows
        float p0 = ((v[0] * a + v[1]) * a + v[2]) * a + v[3];
        float p1 = ((w[0] * a + w[1]) * a + w[2]) * a + w[3];
        float e = p4[7 - quad] * p0 + p4[3 - quad] * p1;   // a^(28-16di-4quad) weights
        e += __shfl_xor(e, 16, 64);
        e += __shfl_xor(e, 32, 64);
        if (quad == 0) {
          const int sg = sB + wr * 4 + sp;    // global segment 0..63
          E[(long)sg * NCH + bb * H_ + c0] = e;
        }
      }
    }
  }
}

// ---------------- scan: per-block Horner carry over E + final scan, in-place (R7-verified) ----------------
__global__ __launch_bounds__(256) void k_scan(float* __restrict__ u,
                                              const float* __restrict__ E,
                                              const float* __restrict__ h0,
                                              const float* __restrict__ a_sig) {
  int g = blockIdx.x * 256 + threadIdx.x;
  int vc = g & (NVC - 1);
  int s  = g >> 11;
  int b  = vc >> 8;
  int h4 = (vc & 255) * 4;
  float4 a = *reinterpret_cast<const float4*>(a_sig + h4);
  float4 aL = a;
  #pragma unroll
  for (int i = 0; i < 5; i++) { aL.x *= aL.x; aL.y *= aL.y; aL.z *= aL.z; aL.w *= aL.w; } // a^32
  float4 hs = *reinterpret_cast<const float4*>(h0 + (long)vc * 4);
  int j = 0;
  for (; j + 8 <= s; j += 8) {
    float4 e[8];
    #pragma unroll
    for (int q = 0; q < 8; q++)
      e[q] = *reinterpret_cast<const float4*>(E + (long)(j + q) * NCH + (long)vc * 4);
    #pragma unroll
    for (int q = 0; q < 8; q++)
      hs = fma4(hs, aL, e[q]);
  }
  for (; j < s; ++j) {
    float4 e = *reinterpret_cast<const float4*>(E + (long)j * NCH + (long)vc * 4);
    hs = fma4(hs, aL, e);
  }

  float* base = u + (long)b * T_ * H_ + (long)s * TSEG * H_ + h4;

  float4 v0[8], v1[8];
  #pragma unroll
  for (int jj = 0; jj < 8; jj++)
    v0[jj] = *reinterpret_cast<const float4*>(base + (long)jj * H_);

  #pragma unroll
  for (int t0 = 0; t0 < TSEG; t0 += 8) {
    const bool odd = (t0 >> 3) & 1;          // compile-time after full unroll
    float4* cur = odd ? v1 : v0;
    float4* nxt = odd ? v0 : v1;
    if (t0 + 8 < TSEG) {
      #pragma unroll
      for (int jj = 0; jj < 8; jj++)
        nxt[jj] = *reinterpret_cast<const float4*>(base + (long)(t0 + 8 + jj) * H_);
    }
    #pragma unroll
    for (int jj = 0; jj < 8; jj++) {
      hs = fma4(hs, a, cur[jj]);
      cur[jj] = hs;
    }
    #pragma unroll
    for (int jj = 0; jj < 8; jj++)
      *reinterpret_cast<float4*>(base + (long)(t0 + jj) * H_) = cur[jj];
  }
}

extern "C" void kernel_launch(void* const* d_in, const int* in_sizes, int n_in,
                              void* d_out, int out_size, void* d_ws, size_t ws_size,
                              hipStream_t stream) {
  const float* x    = (const float*)d_in[0];   // [8,2048,1024]
  const float* rawa = (const float*)d_in[1];   // [1024]
  const float* Bm   = (const float*)d_in[2];   // [1024,1024]
  const float* h0   = (const float*)d_in[3];   // [8,1024]
  float* u = (float*)d_out;                    // u then y, in place

  // Workspace layout (R1-verified footprint):
  // xb 32 MiB | Bb 2 MiB | a_sig 4 KiB | E 2 MiB
  char* w = (char*)d_ws;
  unsigned short* xb = (unsigned short*)w;                               // 32 MiB
  unsigned short* Bb = (unsigned short*)(w + 33554432);                  // 2 MiB
  float* a_sig = (float*)(w + 33554432 + 2097152);                       // 4 KiB
  float* E     = (float*)(w + 33554432 + 2097152 + 4096);                // 2 MiB

  hipLaunchKernelGGL(k_convert, dim3(17409), dim3(256), 0, stream, x, Bm, rawa, xb, Bb, a_sig);
  hipLaunchKernelGGL(k_gemm, dim3(256), dim3(512), 0, stream, xb, Bb, u, a_sig, E);
  hipLaunchKernelGGL(k_scan, dim3(NVC * SEG / 256), dim3(256), 0, stream, u, E, h0, a_sig);
}

// Round 9
// 168.269 us; speedup vs baseline: 1.2005x; 1.0238x over previous
//
#include <hip/hip_runtime.h>
#include <hip/hip_bf16.h>

using bf16 = __hip_bfloat16;
typedef __attribute__((ext_vector_type(8))) short frag8;   // 8 bf16 (4 VGPRs)
typedef __attribute__((ext_vector_type(4))) float f32x4;   // 4 fp32 acc

constexpr int   H_   = 1024;               // N_EMBD
constexpr int   B_   = 8;                  // BATCH
constexpr int   T_   = 2048;
constexpr int   K_   = H_;
constexpr int   N_   = H_;
constexpr long  M_   = (long)B_ * T_;      // 16384
constexpr int   SEG  = 64;                 // segments per sequence
constexpr int   TSEG = T_ / SEG;           // 32
constexpr int   NCH  = B_ * H_;            // 8192 channels
constexpr int   NVC  = NCH / 4;            // 2048 vec4-channels

__device__ __forceinline__ unsigned short f2bf(float f) {
  bf16 b = __float2bfloat16(f);
  return *reinterpret_cast<unsigned short*>(&b);
}
__device__ __forceinline__ float bf2f(unsigned short u) {
  unsigned v = (unsigned)u << 16;
  return *reinterpret_cast<float*>(&v);
}

__device__ __forceinline__ float4 fma4(float4 h, float4 a, float4 v) {
  float4 r;
  r.x = fmaf(h.x, a.x, v.x);
  r.y = fmaf(h.y, a.y, v.y);
  r.z = fmaf(h.z, a.z, v.z);
  r.w = fmaf(h.w, a.w, v.w);
  return r;
}

// ---------------- fp32 -> bf16 convert (x then B) + fused sigmoid ----------------
// R9: 8 floats/thread -> 16B bf16 stores (was 8B).
typedef __attribute__((ext_vector_type(8))) short short8v;
__global__ __launch_bounds__(256) void k_convert(const float* __restrict__ x,
                                                 const float* __restrict__ Bm,
                                                 const float* __restrict__ raw,
                                                 unsigned short* __restrict__ xb,
                                                 unsigned short* __restrict__ Bb,
                                                 float* __restrict__ a_sig) {
  const long NX8 = (M_ * K_) / 8;             // 2097152
  const long NB8 = ((long)N_ * K_) / 8;       // 131072
  long t = (long)blockIdx.x * 256 + threadIdx.x;
  const float* src; unsigned short* dst;
  if (t < NX8) { src = x; dst = xb; }
  else if (t < NX8 + NB8) { t -= NX8; src = Bm; dst = Bb; }
  else {
    long q = t - NX8 - NB8;
    if (q >= H_ / 4) return;
    float4 v = *reinterpret_cast<const float4*>(raw + q * 4);
    float4 o;
    o.x = 1.0f / (1.0f + expf(-v.x));
    o.y = 1.0f / (1.0f + expf(-v.y));
    o.z = 1.0f / (1.0f + expf(-v.z));
    o.w = 1.0f / (1.0f + expf(-v.w));
    *reinterpret_cast<float4*>(a_sig + q * 4) = o;
    return;
  }
  long i = t * 8;
  float4 v0 = *reinterpret_cast<const float4*>(src + i);
  float4 v1 = *reinterpret_cast<const float4*>(src + i + 4);
  short8v o;
  o[0] = (short)f2bf(v0.x); o[1] = (short)f2bf(v0.y);
  o[2] = (short)f2bf(v0.z); o[3] = (short)f2bf(v0.w);
  o[4] = (short)f2bf(v1.x); o[5] = (short)f2bf(v1.y);
  o[6] = (short)f2bf(v1.z); o[7] = (short)f2bf(v1.w);
  *reinterpret_cast<short8v*>(dst + i) = o;
}

// ---------------- bf16 GEMM: 256x256 tile, BK=64, 8-wave, 8-phase counted-vmcnt pipeline ----------------
// R4: T2 XOR swizzle (conflicts 0). R5: one barrier/phase. R8: fused seg_ends epilogue.
// R9: template<UBF> — UBF=1 stores u as bf16 to UB workspace (halves C-write bytes);
//     UBF=0 is the byte-identical R8 behavior (fp32 C to out). Chosen at launch by ws_size.
#define MEMBAR asm volatile("" ::: "memory")
#define BARR do { MEMBAR; __builtin_amdgcn_s_barrier(); MEMBAR; } while (0)
#define VMW(n) asm volatile("s_waitcnt vmcnt(" #n ")" ::: "memory")
#define GLDS(SRC, DST) __builtin_amdgcn_global_load_lds( \
    (const __attribute__((address_space(1))) void*)(SRC), \
    (__attribute__((address_space(3))) void*)(DST), 16, 0, 0)

template<int UBF>
__global__ __launch_bounds__(512, 2) void k_gemm(const unsigned short* __restrict__ A,
                                                 const unsigned short* __restrict__ Bb,
                                                 float* __restrict__ C,
                                                 unsigned short* __restrict__ UB,
                                                 const float* __restrict__ a_sig,
                                                 float* __restrict__ E) {
  __shared__ __align__(16) unsigned short lA[32768];   // 64 KiB
  __shared__ __align__(16) unsigned short lB[32768];   // 64 KiB
  const int tid  = threadIdx.x;
  const int wid  = tid >> 6, lane = tid & 63;
  const int wr   = wid >> 2, wc = wid & 3;             // 2x4 wave grid
  const int quad = lane >> 4, l16 = lane & 15;
  const int sx   = l16 & 7;                            // read-side swizzle key
  const int bh   = wc >> 1, br = (wc & 1) * 64;        // B half / row base for this wave
  const int bid  = blockIdx.x;
  const int wgid = (bid & 7) * 32 + (bid >> 3);        // XCD-chunked swizzle (256%8==0, bijective)
  const long m0 = (long)(wgid >> 2) * 256;
  const long n0 = (long)(wgid & 3) * 256;
  // stage-side: inverse-swizzled global source (same XOR involution)
  const int sgran = (tid & 7) ^ ((tid >> 3) & 7);
  const unsigned short* gA = A  + (m0 + (tid >> 3)) * K_ + sgran * 8;
  const unsigned short* gB = Bb + (n0 + (tid >> 3)) * K_ + sgran * 8;
  unsigned short* sAw = lA + wid * 512;                // wave-uniform LDS dest slice
  unsigned short* sBw = lB + wid * 512;

#define STG_A(d, hf, t) do { \
    GLDS(gA + ((hf) * 128) * K_ + (t) * 64,      sAw + (d) * 16384 + (hf) * 8192); \
    GLDS(gA + ((hf) * 128 + 64) * K_ + (t) * 64, sAw + (d) * 16384 + (hf) * 8192 + 4096); } while (0)
#define STG_B(d, hf, t) do { \
    GLDS(gB + ((hf) * 128) * K_ + (t) * 64,      sBw + (d) * 16384 + (hf) * 8192); \
    GLDS(gB + ((hf) * 128 + 64) * K_ + (t) * 64, sBw + (d) * 16384 + (hf) * 8192 + 4096); } while (0)

  f32x4 acc[8][4];
  #pragma unroll
  for (int i = 0; i < 8; i++)
    #pragma unroll
    for (int j = 0; j < 4; j++) acc[i][j] = f32x4{0.f, 0.f, 0.f, 0.f};

  frag8 aR[4][2];        // current ih-half A frags: [ii][ks]
  frag8 bR[2][2][2];     // both jh halves live:    [jh][jj][ks]

#define RD_A(d, ih) do { _Pragma("unroll") \
    for (int ii = 0; ii < 4; ii++) { \
      const unsigned short* rp = lA + (d) * 16384 + wr * 8192 + (((ih) * 4 + ii) * 16 + l16) * 64; \
      aR[ii][0] = *(const frag8*)(rp + (quad ^ sx) * 8); \
      aR[ii][1] = *(const frag8*)(rp + ((quad + 4) ^ sx) * 8); } } while (0)
#define RD_B(d, jh) do { _Pragma("unroll") \
    for (int jj = 0; jj < 2; jj++) { \
      const unsigned short* rp = lB + (d) * 16384 + bh * 8192 + (br + ((jh) * 2 + jj) * 16 + l16) * 64; \
      bR[jh][jj][0] = *(const frag8*)(rp + (quad ^ sx) * 8); \
      bR[jh][jj][1] = *(const frag8*)(rp + ((quad + 4) ^ sx) * 8); } } while (0)
#define MMQ(ih, jh) do { __builtin_amdgcn_s_setprio(1); _Pragma("unroll") \
    for (int ii = 0; ii < 4; ii++) { _Pragma("unroll") \
      for (int jj = 0; jj < 2; jj++) { \
        acc[(ih)*4+ii][(jh)*2+jj] = __builtin_amdgcn_mfma_f32_16x16x32_bf16(aR[ii][0], bR[jh][jj][0], acc[(ih)*4+ii][(jh)*2+jj], 0, 0, 0); \
        acc[(ih)*4+ii][(jh)*2+jj] = __builtin_amdgcn_mfma_f32_16x16x32_bf16(aR[ii][1], bR[jh][jj][1], acc[(ih)*4+ii][(jh)*2+jj], 0, 0, 0); } } \
    __builtin_amdgcn_s_setprio(0); } while (0)

  // prologue: tile0 all 4 halves + tile1 half A0 (5 halves = 10 loads); need tile0 -> vmcnt(2)
  STG_A(0, 0, 0); STG_A(0, 1, 0); STG_B(0, 0, 0); STG_B(0, 1, 0); STG_A(1, 0, 1);
  VMW(2); BARR;

  for (int it = 0; it < 7; ++it) {
    const int to = 2 * it + 1, te2 = 2 * it + 2, to2 = 2 * it + 3;
    RD_A(0, 0); RD_B(0, 0); STG_A(1, 1, to);          BARR; MMQ(0, 0);  // p1
    RD_B(0, 1);             STG_B(1, 0, to);          BARR; MMQ(0, 1);  // p2
    RD_A(0, 1);             STG_B(1, 1, to);          BARR; MMQ(1, 1);  // p3
                            STG_A(0, 0, te2); VMW(2); BARR; MMQ(1, 0);  // p4
    RD_A(1, 0); RD_B(1, 0); STG_A(0, 1, te2);         BARR; MMQ(0, 0);  // p5
    RD_B(1, 1);             STG_B(0, 0, te2);         BARR; MMQ(0, 1);  // p6
    RD_A(1, 1);             STG_B(0, 1, te2);         BARR; MMQ(1, 1);  // p7
                            STG_A(1, 0, to2); VMW(2); BARR; MMQ(1, 0);  // p8
  }
  // peeled final iteration (tiles 14, 15): p1-3 still stage tile15's remaining halves
  RD_A(0, 0); RD_B(0, 0); STG_A(1, 1, 15);         BARR; MMQ(0, 0);
  RD_B(0, 1);             STG_B(1, 0, 15);         BARR; MMQ(0, 1);
  RD_A(0, 1);             STG_B(1, 1, 15);         BARR; MMQ(1, 1);
                                           VMW(0); BARR; MMQ(1, 0);
  RD_A(1, 0); RD_B(1, 0);                          BARR; MMQ(0, 0);
  RD_B(1, 1);                                      BARR; MMQ(0, 1);
  RD_A(1, 1);                                      BARR; MMQ(1, 1);
  MMQ(1, 0);

  // epilogue 1: u-store. C/D layout col=l16, row=quad*4+r (m89-verified mapping)
  #pragma unroll
  for (int i = 0; i < 8; i++)
    #pragma unroll
    for (int j = 0; j < 4; j++) {
      const long r0 = m0 + wr * 128 + i * 16 + quad * 4;
      const long c0 = n0 + wc * 64 + j * 16 + l16;
      #pragma unroll
      for (int r = 0; r < 4; r++) {
        if (UBF) UB[(r0 + r) * N_ + c0] = f2bf(acc[i][j][r]);
        else     C [(r0 + r) * N_ + c0] = acc[i][j][r];
      }
    }

  // epilogue 2 (R8-verified): fused seg_ends. tau = 16*(i&1) + 4*quad + r.
  {
    const int bb = (int)(m0 >> 11);           // batch
    const int sB = (int)((m0 & 2047) >> 5);   // first global segment of this tile
    #pragma unroll
    for (int j = 0; j < 4; j++) {
      const int c0 = (int)(n0) + wc * 64 + j * 16 + l16;   // channel h (0..1023)
      const float a  = a_sig[c0];
      const float a2 = a * a, a4 = a2 * a2;
      float p4[8];
      p4[0] = 1.f;
      #pragma unroll
      for (int k = 1; k < 8; k++) p4[k] = p4[k - 1] * a4;
      #pragma unroll
      for (int sp = 0; sp < 4; sp++) {        // segment pair = i>>1
        const f32x4 v = acc[sp * 2][j];       // di = 0 rows
        const f32x4 w = acc[sp * 2 + 1][j];   // di = 1 rows
        float p0 = ((v[0] * a + v[1]) * a + v[2]) * a + v[3];
        float p1 = ((w[0] * a + w[1]) * a + w[2]) * a + w[3];
        float e = p4[7 - quad] * p0 + p4[3 - quad] * p1;   // a^(28-16di-4quad) weights
        e += __shfl_xor(e, 16, 64);
        e += __shfl_xor(e, 32, 64);
        if (quad == 0) {
          const int sg = sB + wr * 4 + sp;    // global segment 0..63
          E[(long)sg * NCH + bb * H_ + c0] = e;
        }
      }
    }
  }
}

// ---------------- scan (fallback, R7-verified): Horner carry + in-place fp32 scan ----------------
__global__ __launch_bounds__(256) void k_scan(float* __restrict__ u,
                                              const float* __restrict__ E,
                                              const float* __restrict__ h0,
                                              const float* __restrict__ a_sig) {
  int g = blockIdx.x * 256 + threadIdx.x;
  int vc = g & (NVC - 1);
  int s  = g >> 11;
  int b  = vc >> 8;
  int h4 = (vc & 255) * 4;
  float4 a = *reinterpret_cast<const float4*>(a_sig + h4);
  float4 aL = a;
  #pragma unroll
  for (int i = 0; i < 5; i++) { aL.x *= aL.x; aL.y *= aL.y; aL.z *= aL.z; aL.w *= aL.w; } // a^32
  float4 hs = *reinterpret_cast<const float4*>(h0 + (long)vc * 4);
  int j = 0;
  for (; j + 8 <= s; j += 8) {
    float4 e[8];
    #pragma unroll
    for (int q = 0; q < 8; q++)
      e[q] = *reinterpret_cast<const float4*>(E + (long)(j + q) * NCH + (long)vc * 4);
    #pragma unroll
    for (int q = 0; q < 8; q++)
      hs = fma4(hs, aL, e[q]);
  }
  for (; j < s; ++j) {
    float4 e = *reinterpret_cast<const float4*>(E + (long)j * NCH + (long)vc * 4);
    hs = fma4(hs, aL, e);
  }

  float* base = u + (long)b * T_ * H_ + (long)s * TSEG * H_ + h4;
  float4 v0[8], v1[8];
  #pragma unroll
  for (int jj = 0; jj < 8; jj++)
    v0[jj] = *reinterpret_cast<const float4*>(base + (long)jj * H_);
  #pragma unroll
  for (int t0 = 0; t0 < TSEG; t0 += 8) {
    const bool odd = (t0 >> 3) & 1;
    float4* cur = odd ? v1 : v0;
    float4* nxt = odd ? v0 : v1;
    if (t0 + 8 < TSEG) {
      #pragma unroll
      for (int jj = 0; jj < 8; jj++)
        nxt[jj] = *reinterpret_cast<const float4*>(base + (long)(t0 + 8 + jj) * H_);
    }
    #pragma unroll
    for (int jj = 0; jj < 8; jj++) {
      hs = fma4(hs, a, cur[jj]);
      cur[jj] = hs;
    }
    #pragma unroll
    for (int jj = 0; jj < 8; jj++)
      *reinterpret_cast<float4*>(base + (long)(t0 + jj) * H_) = cur[jj];
  }
}

// ---------------- scan (R9): reads bf16-u from workspace, writes fp32 y to out ----------------
__global__ __launch_bounds__(256) void k_scan_bf(float* __restrict__ y,
                                                 const unsigned short* __restrict__ ub,
                                                 const float* __restrict__ E,
                                                 const float* __restrict__ h0,
                                                 const float* __restrict__ a_sig) {
  int g = blockIdx.x * 256 + threadIdx.x;
  int vc = g & (NVC - 1);
  int s  = g >> 11;
  int b  = vc >> 8;
  int h4 = (vc & 255) * 4;
  float4 a = *reinterpret_cast<const float4*>(a_sig + h4);
  float4 aL = a;
  #pragma unroll
  for (int i = 0; i < 5; i++) { aL.x *= aL.x; aL.y *= aL.y; aL.z *= aL.z; aL.w *= aL.w; } // a^32
  float4 hs = *reinterpret_cast<const float4*>(h0 + (long)vc * 4);
  int j = 0;
  for (; j + 8 <= s; j += 8) {
    float4 e[8];
    #pragma unroll
    for (int q = 0; q < 8; q++)
      e[q] = *reinterpret_cast<const float4*>(E + (long)(j + q) * NCH + (long)vc * 4);
    #pragma unroll
    for (int q = 0; q < 8; q++)
      hs = fma4(hs, aL, e[q]);
  }
  for (; j < s; ++j) {
    float4 e = *reinterpret_cast<const float4*>(E + (long)j * NCH + (long)vc * 4);
    hs = fma4(hs, aL, e);
  }

  const long row0 = (long)b * T_ + (long)s * TSEG;
  const unsigned short* ubase = ub + row0 * H_ + h4;
  float* ybase = y + row0 * H_ + h4;

  short4 v0[8], v1[8];
  #pragma unroll
  for (int jj = 0; jj < 8; jj++)
    v0[jj] = *reinterpret_cast<const short4*>(ubase + (long)jj * H_);
  #pragma unroll
  for (int t0 = 0; t0 < TSEG; t0 += 8) {
    const bool odd = (t0 >> 3) & 1;
    short4* cur = odd ? v1 : v0;
    short4* nxt = odd ? v0 : v1;
    if (t0 + 8 < TSEG) {
      #pragma unroll
      for (int jj = 0; jj < 8; jj++)
        nxt[jj] = *reinterpret_cast<const short4*>(ubase + (long)(t0 + 8 + jj) * H_);
    }
    #pragma unroll
    for (int jj = 0; jj < 8; jj++) {
      float4 v;
      v.x = bf2f((unsigned short)cur[jj].x);
      v.y = bf2f((unsigned short)cur[jj].y);
      v.z = bf2f((unsigned short)cur[jj].z);
      v.w = bf2f((unsigned short)cur[jj].w);
      hs = fma4(hs, a, v);
      *reinterpret_cast<float4*>(ybase + (long)(t0 + jj) * H_) = hs;
    }
  }
}

extern "C" void kernel_launch(void* const* d_in, const int* in_sizes, int n_in,
                              void* d_out, int out_size, void* d_ws, size_t ws_size,
                              hipStream_t stream) {
  const float* x    = (const float*)d_in[0];   // [8,2048,1024]
  const float* rawa = (const float*)d_in[1];   // [1024]
  const float* Bm   = (const float*)d_in[2];   // [1024,1024]
  const float* h0   = (const float*)d_in[3];   // [8,1024]
  float* u = (float*)d_out;                    // u then y, in place (fallback path)

  // Workspace: xb 32MiB | Bb 2MiB | a_sig 4KiB | E 2MiB | [ub 32MiB if ws allows]
  char* w = (char*)d_ws;
  unsigned short* xb = (unsigned short*)w;                               // 32 MiB
  unsigned short* Bb = (unsigned short*)(w + 33554432);                  // 2 MiB
  float* a_sig = (float*)(w + 33554432 + 2097152);                       // 4 KiB
  float* E     = (float*)(w + 33554432 + 2097152 + 4096);                // 2 MiB
  unsigned short* ub = (unsigned short*)(w + 37752832);                  // 32 MiB (offset 36.004 MiB)
  const bool big_ws = (ws_size >= (size_t)37752832 + 33554432);

  hipLaunchKernelGGL(k_convert, dim3(8705), dim3(256), 0, stream, x, Bm, rawa, xb, Bb, a_sig);
  if (big_ws) {
    hipLaunchKernelGGL(HIP_KERNEL_NAME(k_gemm<1>), dim3(256), dim3(512), 0, stream,
                       xb, Bb, u, ub, a_sig, E);
    hipLaunchKernelGGL(k_scan_bf, dim3(NVC * SEG / 256), dim3(256), 0, stream,
                       u, ub, E, h0, a_sig);
  } else {
    hipLaunchKernelGGL(HIP_KERNEL_NAME(k_gemm<0>), dim3(256), dim3(512), 0, stream,
                       xb, Bb, u, ub, a_sig, E);
    hipLaunchKernelGGL(k_scan, dim3(NVC * SEG / 256), dim3(256), 0, stream,
                       u, E, h0, a_sig);
  }
}